// Round 11
// baseline (525.304 us; speedup 1.0000x reference)
//
#include <hip/hip_runtime.h>

// ---------------------------------------------------------------------------
// Actor: GRU over V=20 vehicle slots (H=256) + MLP head 271->1024->1024->512->256->1
// B=16384, F=15. All GEMMs in bf16 MFMA (16x16x32), fp32 accumulate.
//
// Round-25: two changes.
// (1) gemm3/4 reverted to the 128x128 2-phase kernel (r24's BM=64 was
//     neutral-negative; r23 = 445.1 us is session best).
// (2) GRU: retry r20's held-weight merged single-pass with
//     __launch_bounds__(512, 1). Law fit over r15-r21: VGPR = 2048/(arg x
//     block_waves); arg=1 at wg-512 predicts 256 VGPR/wave (1 block/CU,
//     2 waves/SIMD x 256 = full file, no pairing requested). r20's liveness
//     ~222 fits. Streams: weights halved by register-holding jt0 (L2 32us),
//     merged pass (LDS ~30us), MFMA 66us. r20 hit 354us WITH spill at the
//     128 cap; without spill ~200us is the model. Decisive counter: VGPR
//     ~220 + FETCH ~12MB = success; VGPR 128 + FETCH 0.5GB = clamp is hard,
//     revert next round.
// ---------------------------------------------------------------------------

typedef __attribute__((ext_vector_type(8))) __bf16 bf16x8;
typedef __attribute__((ext_vector_type(4))) __bf16 bf16x4;
typedef __attribute__((ext_vector_type(4))) float  floatx4;

#define MFMA16(a, b, c) __builtin_amdgcn_mfma_f32_16x16x32_bf16((a), (b), (c), 0, 0, 0)

#define GL_LDS16(g, l)                                                         \
    __builtin_amdgcn_global_load_lds(                                          \
        (const __attribute__((address_space(1))) void*)(g),                    \
        (__attribute__((address_space(3))) void*)(l), 16, 0, 0)

__device__ __forceinline__ float sigmoid_f(float x) { return 1.f / (1.f + __expf(-x)); }
__device__ __forceinline__ float tanh_f(float x)    { return 1.f - 2.f / (1.f + __expf(2.f * x)); }

// ---------------------------------------------------------------------------
// Weight prep:
//   Wg1  [512][288]  rows g in {r(0..255), z(256..511)}:
//        [W_ih[g][0..14] | bsum[g] | 0 x16 | W_hh[g][0..255]]   (col 15 = bias)
//   W1p  [1024][288] : [W1[o][0..14] | 0 x17 | W1[o][15..270]]
//   W2b  [1024][1024], W3b [512][1024], W4b [256][512]  : direct cvt
//   Win_n[256][32]   : [W_ih[512+j][0..14] | b_ih[512+j] | 0 x16] (col 15 = bias)
//   Whh_n[256][256]  : W_hh rows 512..767
//   bhhn [256] = b_hh[512+]
// ---------------------------------------------------------------------------
#define S0 147456u
#define S1 442368u
#define S2 1490944u
#define S3 2015232u
#define S4 2146304u
#define S5 2154496u
#define S6 2220032u
#define S7 2220544u
#define S8 2221056u

__global__ void prep_kernel(const float* __restrict__ W_ih, const float* __restrict__ W_hh,
                            const float* __restrict__ b_ih, const float* __restrict__ b_hh,
                            const float* __restrict__ W1, const float* __restrict__ W2,
                            const float* __restrict__ W3, const float* __restrict__ W4,
                            __bf16* __restrict__ Wg1, __bf16* __restrict__ W1p,
                            __bf16* __restrict__ W2b, __bf16* __restrict__ W3b,
                            __bf16* __restrict__ W4b, __bf16* __restrict__ Win_n,
                            __bf16* __restrict__ Whh_n, float* __restrict__ bsum,
                            float* __restrict__ bihn, float* __restrict__ bhhn)
{
    for (unsigned i = blockIdx.x * blockDim.x + threadIdx.x; i < S8; i += gridDim.x * blockDim.x) {
        if (i < S0) {
            unsigned g = i / 288u, c = i % 288u;
            float v;
            if (c < 15u)       v = W_ih[g * 15u + c];
            else if (c == 15u) v = b_ih[g] + b_hh[g];          // folded r/z bias
            else if (c < 32u)  v = 0.f;
            else               v = W_hh[g * 256u + (c - 32u)];
            Wg1[i] = (__bf16)v;
        } else if (i < S1) {
            unsigned t = i - S0, o = t / 288u, c = t % 288u;
            float v = (c < 15u) ? W1[o * 271u + c] : ((c < 32u) ? 0.f : W1[o * 271u + (c - 17u)]);
            W1p[t] = (__bf16)v;
        } else if (i < S2) {
            unsigned t = i - S1; W2b[t] = (__bf16)W2[t];
        } else if (i < S3) {
            unsigned t = i - S2; W3b[t] = (__bf16)W3[t];
        } else if (i < S4) {
            unsigned t = i - S3; W4b[t] = (__bf16)W4[t];
        } else if (i < S5) {
            unsigned t = i - S4, j = t / 32u, c = t % 32u;
            float v;
            if (c < 15u)       v = W_ih[(512u + j) * 15u + c];
            else if (c == 15u) v = b_ih[512u + j];             // folded xn bias
            else               v = 0.f;
            Win_n[t] = (__bf16)v;
        } else if (i < S6) {
            unsigned t = i - S5; Whh_n[t] = (__bf16)W_hh[512u * 256u + t];
        } else if (i < S7) {
            unsigned t = i - S6; bsum[t] = b_ih[t] + b_hh[t];
        } else {
            unsigned t = i - S7;
            if (t < 256u) bihn[t] = b_ih[512u + t];
            else          bhhn[t - 256u] = b_hh[512u + t - 256u];
        }
    }
}

// ---------------------------------------------------------------------------
// GRU kernel (r20 structure + launch_bounds(512,1)). 256 blocks x 512 threads
// (8 waves). 64 batch rows/block. Wave w owns gate cols w*32..w*32+31:
// jt0 (first 16) weights HELD in registers across all 20 steps (27 bf16x8
// frags = 108 VGPR), jt1 (second 16) streamed from L2 each step. Per jt:
// {ar,az,ah} accumulate over the h tile with ONE shared h-fragment read per
// (kk,nt) feeding all 3 gate MFMAs, {ar,az,ax} over the state slab, then
// fused epilogue (r,z fp32 sigmoid in regs, n = tanh(ax + r*(ah+bhn)),
// h' = (1-z)n + z*h_old read from hbuf[SB]). hbuf double-buffered,
// 1 barrier/step. sbuf stride 40: conflict-free.
// ---------------------------------------------------------------------------
#define HSTRIDE 264
#define HBUF_N  (64 * HSTRIDE)    // 16896
#define SSTRIDE 40
#define SBUF_N  (64 * SSTRIDE)    // 2560 per buffer

__global__ __launch_bounds__(512, 1)
void gru_kernel(const float* __restrict__ state,
                const __bf16* __restrict__ Wg1,  const __bf16* __restrict__ Win_n,
                const __bf16* __restrict__ Whh_n,
                const float* __restrict__ bhhn, __bf16* __restrict__ x0)
{
    __shared__ __bf16 hbuf[2 * HBUF_N];        // 67584 B
    __shared__ __bf16 sbuf[2 * SBUF_N];        // 10240 B; k 16..39 zero, k15 = 1.0

    const int tid  = threadIdx.x;
    const int wave = tid >> 6;    // 0..7 : 32-col group
    const int lane = tid & 63;
    const int q    = lane >> 4;
    const int ln   = lane & 15;
    const int b0   = blockIdx.x * 64;

    {   // zero h buffer 0 and both sbuf buffers
        bf16x8 z = {};
        bf16x8* p = (bf16x8*)hbuf;
        #pragma unroll
        for (int t = 0; t < 5; t++) {
            int i = tid + t * 512;
            if (i < HBUF_N / 8) p[i] = z;
        }
        #pragma unroll
        for (int t = 0; t < 2; t++) {
            int i = tid + t * 512;
            if (i < 2 * SBUF_N / 8) ((bf16x8*)sbuf)[i] = z;
        }
    }
    const int srow = tid >> 4, sk = tid & 15;   // 32 rows x 16 cols; rows srow, srow+32

    const __bf16* hread  = hbuf + ln * HSTRIDE + q * 8;              // + nt*16*HSTRIDE
    __bf16*       hwrite = hbuf + ln * HSTRIDE + wave * 32 + q * 4;  // + jt*16 + nt*16*HSTRIDE
    const __bf16* sread  = sbuf + ln * SSTRIDE + q * 8;              // + nt*16*SSTRIDE

    // ---- held jt0 weight fragments (loop-invariant across all 20 steps) ----
    const unsigned jr0 = (unsigned)(wave * 32 + ln);
    const __bf16* wr0 = Wg1   + jr0 * 288u + q * 8u;
    const __bf16* wz0 = wr0 + 256u * 288u;
    const __bf16* wh0 = Whh_n + jr0 * 256u + q * 8u;
    const __bf16* wx0 = Win_n + jr0 * 32u  + q * 8u;
    bf16x8 Wr[9], Wz[9], Wh[8], Wx;
    #pragma unroll
    for (int kk = 0; kk < 8; kk++) {
        Wr[kk] = *(const bf16x8*)(wr0 + 32 + kk * 32);
        Wz[kk] = *(const bf16x8*)(wz0 + 32 + kk * 32);
        Wh[kk] = *(const bf16x8*)(wh0 + kk * 32);
    }
    Wr[8] = *(const bf16x8*)(wr0);
    Wz[8] = *(const bf16x8*)(wz0);
    Wx    = *(const bf16x8*)(wx0);
    const floatx4 Bhn0 = *(const floatx4*)(bhhn + wave * 32 + q * 4);
    const floatx4 Bhn1 = *(const floatx4*)(bhhn + wave * 32 + 16 + q * 4);

    // ---- streamed jt1 weight pointers ----
    const unsigned jr1 = jr0 + 16u;
    const __bf16* wr1 = Wg1   + jr1 * 288u + q * 8u;
    const __bf16* wz1 = wr1 + 256u * 288u;
    const __bf16* wh1 = Whh_n + jr1 * 256u + q * 8u;
    const __bf16* wx1 = Win_n + jr1 * 32u  + q * 8u;

    // stage state slice v=0, then set the permanent 1.0 bias column (k=15)
    if (sk < 15) {
        sbuf[srow * SSTRIDE + sk] = (__bf16)state[(size_t)(b0 + srow) * 300 + sk];
        sbuf[(srow + 32) * SSTRIDE + sk] = (__bf16)state[(size_t)(b0 + srow + 32) * 300 + sk];
    }
    if (tid < 128) sbuf[(tid >> 6) * SBUF_N + (tid & 63) * SSTRIDE + 15] = (__bf16)1.0f;
    __syncthreads();

#define GRU_STEP(v, SB)                                                          \
    {                                                                            \
        float sn0 = 0.f, sn1 = 0.f;                                              \
        if ((v) < 19 && sk < 15) {                                               \
            sn0 = state[(size_t)(b0 + srow) * 300 + ((v) + 1) * 15 + sk];        \
            sn1 = state[(size_t)(b0 + srow + 32) * 300 + ((v) + 1) * 15 + sk];   \
        }                                                                        \
        const floatx4 zf = {0.f, 0.f, 0.f, 0.f};                                 \
        {   /* ---- jt0: held weights ---- */                                    \
            floatx4 ar[4], az[4], ah[4], ax[4];                                  \
            _Pragma("unroll")                                                    \
            for (int nt = 0; nt < 4; nt++) { ar[nt]=zf; az[nt]=zf; ah[nt]=zf; }  \
            _Pragma("unroll")                                                    \
            for (int kk = 0; kk < 8; ++kk) {                                     \
                _Pragma("unroll")                                                \
                for (int nt = 0; nt < 4; nt++) {                                 \
                    bf16x8 b = *(const bf16x8*)(hread + (SB) * HBUF_N +          \
                                                nt * (16 * HSTRIDE) + kk * 32);  \
                    ar[nt] = MFMA16(Wr[kk], b, ar[nt]);                          \
                    az[nt] = MFMA16(Wz[kk], b, az[nt]);                          \
                    ah[nt] = MFMA16(Wh[kk], b, ah[nt]);                          \
                }                                                                \
            }                                                                    \
            _Pragma("unroll")                                                    \
            for (int nt = 0; nt < 4; nt++) {                                     \
                bf16x8 b = *(const bf16x8*)(sread + (SB) * SBUF_N +              \
                                            nt * (16 * SSTRIDE));                \
                ar[nt] = MFMA16(Wr[8], b, ar[nt]);                               \
                az[nt] = MFMA16(Wz[8], b, az[nt]);                               \
                ax[nt] = MFMA16(Wx,    b, zf);                                   \
            }                                                                    \
            _Pragma("unroll")                                                    \
            for (int nt = 0; nt < 4; nt++) {                                     \
                bf16x4 ho = *(const bf16x4*)(hwrite + (SB) * HBUF_N +            \
                                             nt * (16 * HSTRIDE));               \
                bf16x4 hv;                                                       \
                _Pragma("unroll")                                                \
                for (int r = 0; r < 4; r++) {                                    \
                    float rg = sigmoid_f(ar[nt][r]);                             \
                    float zg = sigmoid_f(az[nt][r]);                             \
                    float nn = tanh_f(ax[nt][r] + rg * (ah[nt][r] + Bhn0[r]));   \
                    hv[r] = (__bf16)((1.f - zg) * nn + zg * (float)ho[r]);       \
                }                                                                \
                *(bf16x4*)(hwrite + (1 - (SB)) * HBUF_N +                        \
                           nt * (16 * HSTRIDE)) = hv;                            \
            }                                                                    \
        }                                                                        \
        {   /* ---- jt1: streamed weights ---- */                                \
            floatx4 ar[4], az[4], ah[4], ax[4];                                  \
            _Pragma("unroll")                                                    \
            for (int nt = 0; nt < 4; nt++) { ar[nt]=zf; az[nt]=zf; ah[nt]=zf; }  \
            _Pragma("unroll")                                                    \
            for (int kk = 0; kk < 8; ++kk) {                                     \
                bf16x8 a0 = *(const bf16x8*)(wr1 + 32 + kk * 32);                \
                bf16x8 a1 = *(const bf16x8*)(wz1 + 32 + kk * 32);                \
                bf16x8 a2 = *(const bf16x8*)(wh1 + kk * 32);                     \
                _Pragma("unroll")                                                \
                for (int nt = 0; nt < 4; nt++) {                                 \
                    bf16x8 b = *(const bf16x8*)(hread + (SB) * HBUF_N +          \
                                                nt * (16 * HSTRIDE) + kk * 32);  \
                    ar[nt] = MFMA16(a0, b, ar[nt]);                              \
                    az[nt] = MFMA16(a1, b, az[nt]);                              \
                    ah[nt] = MFMA16(a2, b, ah[nt]);                              \
                }                                                                \
            }                                                                    \
            {                                                                    \
                bf16x8 a0 = *(const bf16x8*)(wr1);                               \
                bf16x8 a1 = *(const bf16x8*)(wz1);                               \
                bf16x8 a2 = *(const bf16x8*)(wx1);                               \
                _Pragma("unroll")                                                \
                for (int nt = 0; nt < 4; nt++) {                                 \
                    bf16x8 b = *(const bf16x8*)(sread + (SB) * SBUF_N +          \
                                                nt * (16 * SSTRIDE));            \
                    ar[nt] = MFMA16(a0, b, ar[nt]);                              \
                    az[nt] = MFMA16(a1, b, az[nt]);                              \
                    ax[nt] = MFMA16(a2, b, zf);                                  \
                }                                                                \
            }                                                                    \
            _Pragma("unroll")                                                    \
            for (int nt = 0; nt < 4; nt++) {                                     \
                bf16x4 ho = *(const bf16x4*)(hwrite + 16 + (SB) * HBUF_N +       \
                                             nt * (16 * HSTRIDE));               \
                bf16x4 hv;                                                       \
                _Pragma("unroll")                                                \
                for (int r = 0; r < 4; r++) {                                    \
                    float rg = sigmoid_f(ar[nt][r]);                             \
                    float zg = sigmoid_f(az[nt][r]);                             \
                    float nn = tanh_f(ax[nt][r] + rg * (ah[nt][r] + Bhn1[r]));   \
                    hv[r] = (__bf16)((1.f - zg) * nn + zg * (float)ho[r]);       \
                }                                                                \
                *(bf16x4*)(hwrite + 16 + (1 - (SB)) * HBUF_N +                   \
                           nt * (16 * HSTRIDE)) = hv;                            \
            }                                                                    \
        }                                                                        \
        if ((v) < 19 && sk < 15) {                                               \
            sbuf[(1 - (SB)) * SBUF_N + srow * SSTRIDE + sk] = (__bf16)sn0;       \
            sbuf[(1 - (SB)) * SBUF_N + (srow + 32) * SSTRIDE + sk] = (__bf16)sn1;\
        }                                                                        \
        __syncthreads();                                                         \
    }

    #pragma unroll 1
    for (int v2 = 0; v2 < 10; ++v2) {
        GRU_STEP(2 * v2,     0)
        GRU_STEP(2 * v2 + 1, 1)
    }
#undef GRU_STEP

    // ---- epilogue: final h is in hbuf buffer 0 (step 19 wrote 1-SB = 0) ----
    // x0 = [state[:,0,:] (15) | 0-pad to 32 | h (256)], coalesced b128 moves.
    {
        const int erow = tid >> 3, p = tid & 7;    // 64 rows x 8 segs
        #pragma unroll
        for (int s = 0; s < 4; s++) {
            const int col = p * 8 + s * 64;
            *(bf16x8*)(x0 + (size_t)(b0 + erow) * 288 + 32 + col) =
                *(const bf16x8*)(hbuf + erow * HSTRIDE + col);
        }
    }
    #pragma unroll
    for (int t = 0; t < 4; t++) {
        int i = tid + t * 512;
        int erow = i >> 5, c = i & 31;
        float s = (c < 15) ? state[(size_t)(b0 + erow) * 300 + c] : 0.f;
        x0[(size_t)(b0 + erow) * 288 + c] = (__bf16)s;
    }
}

// ---------------------------------------------------------------------------
// LDS-staged GEMM, BK=32 double-buffered (T3 minimum 2-phase):
// C = act(A[M][K] @ W[N][K]^T + bias), bf16. 256 thr (4 waves 2x2), tile
// 128x128. Loads for slab k+1 issued AFTER the barrier and BEFORE compute
// of slab k -> the vmcnt(0) drain at the next barrier lands one compute
// phase later. Staging 32KB inside the 34.8KB bounce union (4 blocks/CU).
// ---------------------------------------------------------------------------
__global__ __launch_bounds__(256)
void gemm_bias_act(const __bf16* __restrict__ A, const __bf16* __restrict__ W,
                   const float* __restrict__ bias, __bf16* __restrict__ C,
                   int N, int K, int relu)
{
    __shared__ __bf16 smem[128 * 136];           // 34816 B (bounce; staging in first 32KB)
    // staging (bf16 units): buf0 A @0, B @4096; buf1 A @8192, B @12288

    const int tid  = threadIdx.x;
    const int wave = tid >> 6, lane = tid & 63;
    const int q = lane >> 4, ln = lane & 15;
    const int wm = wave >> 1, wn = wave & 1;
    const int arow0 = blockIdx.x * 128;
    const int bcol0 = blockIdx.y * 128;

    float bv[4];
    #pragma unroll
    for (int n = 0; n < 4; n++) bv[n] = bias[bcol0 + wn * 64 + n * 16 + ln];

    floatx4 acc[4][4];
    const floatx4 zf = {0.f, 0.f, 0.f, 0.f};
    #pragma unroll
    for (int m = 0; m < 4; m++)
        #pragma unroll
        for (int n = 0; n < 4; n++) acc[m][n] = zf;

    const int stg_row = wave * 16 + (lane >> 2);   // + rd*64
    const int stg_k   = (lane & 3) * 8;
    const int lds_off = wave * 512;                // + rd*2048

#define STAGE(kt, b)                                                            \
    {                                                                           \
        _Pragma("unroll")                                                       \
        for (int rd = 0; rd < 2; rd++) {                                        \
            GL_LDS16(A + (size_t)(arow0 + stg_row + rd * 64) * K + (kt) * 32 + stg_k, \
                     smem + (b) * 8192 + lds_off + rd * 2048);                  \
            GL_LDS16(W + (size_t)(bcol0 + stg_row + rd * 64) * K + (kt) * 32 + stg_k, \
                     smem + 4096 + (b) * 8192 + lds_off + rd * 2048);           \
        }                                                                       \
    }

#define GCOMPUTE(b)                                                             \
    {                                                                           \
        bf16x8 af[4], bf[4];                                                    \
        _Pragma("unroll")                                                       \
        for (int m = 0; m < 4; m++)                                             \
            af[m] = *(const bf16x8*)(smem + (b) * 8192 +                        \
                                     (wm * 64 + m * 16 + ln) * 32 + q * 8);     \
        _Pragma("unroll")                                                       \
        for (int n = 0; n < 4; n++)                                             \
            bf[n] = *(const bf16x8*)(smem + 4096 + (b) * 8192 +                 \
                                     (wn * 64 + n * 16 + ln) * 32 + q * 8);     \
        _Pragma("unroll")                                                       \
        for (int n = 0; n < 4; n++)                                             \
            _Pragma("unroll")                                                   \
            for (int m = 0; m < 4; m++)                                         \
                acc[m][n] = MFMA16(af[m], bf[n], acc[m][n]);                    \
    }

    const int nk = K >> 5;          // K multiple of 32 for all layers
    STAGE(0, 0)
    int kt = 0;
    #pragma unroll 1
    for (; kt + 2 <= nk; kt += 2) {
        __syncthreads();                 // buf0 slab ready; buf1 free
        if (kt + 1 < nk) STAGE(kt + 1, 1)
        GCOMPUTE(0)                      // compute slab kt while kt+1 loads fly
        __syncthreads();                 // buf1 slab ready; buf0 free
        if (kt + 2 < nk) STAGE(kt + 2, 0)
        GCOMPUTE(1)                      // compute slab kt+1 while kt+2 loads fly
    }
    if (kt < nk) {                       // odd slab count (gemm1: nk=9)
        __syncthreads();
        GCOMPUTE(0)
    }
    __syncthreads();                     // staging reads done -> bounce may reuse
#undef STAGE
#undef GCOMPUTE

    // epilogue: bias+act -> LDS bounce (stride 136) -> coalesced b128 stores
    #pragma unroll
    for (int m = 0; m < 4; m++)
        #pragma unroll
        for (int n = 0; n < 4; n++)
            #pragma unroll
            for (int r = 0; r < 4; r++) {
                float val = acc[m][n][r] + bv[n];
                if (relu) val = fmaxf(val, 0.f);
                smem[(wm * 64 + m * 16 + q * 4 + r) * 136 + wn * 64 + n * 16 + ln] = (__bf16)val;
            }
    __syncthreads();
    {
        const int row = tid >> 4, seg = tid & 15;
        #pragma unroll
        for (int p = 0; p < 8; p++) {
            const int rr = row + p * 16;
            *(bf16x8*)(C + (size_t)(arow0 + rr) * N + bcol0 + seg * 8) =
                *(const bf16x8*)(smem + rr * 136 + seg * 8);
        }
    }
}

// ---------------------------------------------------------------------------
// Head: out[b] = tanh(dot(x4[b][0..255], Wp) + bp).  4 lanes per row.
// ---------------------------------------------------------------------------
__global__ __launch_bounds__(256)
void head_kernel(const __bf16* __restrict__ x4, const float* __restrict__ Wp,
                 const float* __restrict__ bp, float* __restrict__ out)
{
    const int tid = threadIdx.x;
    const int wave = tid >> 6, lane = tid & 63;
    const int row = blockIdx.x * 64 + wave * 16 + (lane >> 2);
    const int part = lane & 3;
    const __bf16* xp = x4 + (size_t)row * 256 + part * 64;
    const float* wp = Wp + part * 64;
    float sum = 0.f;
    #pragma unroll
    for (int i = 0; i < 8; i++) {
        bf16x8 xv = *(const bf16x8*)(xp + i * 8);
        #pragma unroll
        for (int jj = 0; jj < 8; jj++) sum += (float)xv[jj] * wp[i * 8 + jj];
    }
    sum += __shfl_xor(sum, 1);
    sum += __shfl_xor(sum, 2);
    if (part == 0) out[row] = tanhf(sum + bp[0]);
}

// ---------------------------------------------------------------------------
extern "C" void kernel_launch(void* const* d_in, const int* in_sizes, int n_in,
                              void* d_out, int out_size, void* d_ws, size_t ws_size,
                              hipStream_t stream)
{
    const float* state = (const float*)d_in[0];
    const float* W_ih  = (const float*)d_in[1];
    const float* W_hh  = (const float*)d_in[2];
    const float* b_ih  = (const float*)d_in[3];
    const float* b_hh  = (const float*)d_in[4];
    const float* W1    = (const float*)d_in[5];
    const float* b1    = (const float*)d_in[6];
    const float* W2    = (const float*)d_in[7];
    const float* b2    = (const float*)d_in[8];
    const float* W3    = (const float*)d_in[9];
    const float* b3    = (const float*)d_in[10];
    const float* W4    = (const float*)d_in[11];
    const float* b4    = (const float*)d_in[12];
    const float* Wp    = (const float*)d_in[13];
    const float* bp    = (const float*)d_in[14];
    float* out = (float*)d_out;

    char* ws = (char*)d_ws;
    size_t off = 0;
    auto alloc = [&](size_t bytes) -> void* {
        void* p = ws + off;
        off += (bytes + 255) & ~(size_t)255;
        return p;
    };
    __bf16* Wg1   = (__bf16*)alloc(512 * 288 * 2);
    __bf16* W1p   = (__bf16*)alloc(1024 * 288 * 2);
    __bf16* W2b   = (__bf16*)alloc(1024 * 1024 * 2);
    __bf16* W3b   = (__bf16*)alloc(512 * 1024 * 2);
    __bf16* W4b   = (__bf16*)alloc(256 * 512 * 2);
    __bf16* Win_n = (__bf16*)alloc(256 * 32 * 2);
    __bf16* Whh_n = (__bf16*)alloc(256 * 256 * 2);
    float*  bsum  = (float*)alloc(512 * 4);
    float*  bihn  = (float*)alloc(256 * 4);
    float*  bhhn  = (float*)alloc(256 * 4);
    __bf16* x0    = (__bf16*)alloc((size_t)16384 * 288 * 2);
    __bf16* xA    = (__bf16*)alloc((size_t)16384 * 1024 * 2);
    __bf16* xB    = (__bf16*)alloc((size_t)16384 * 1024 * 2);

    prep_kernel<<<2048, 256, 0, stream>>>(W_ih, W_hh, b_ih, b_hh, W1, W2, W3, W4,
                                          Wg1, W1p, W2b, W3b, W4b, Win_n, Whh_n,
                                          bsum, bihn, bhhn);
    gru_kernel<<<256, 512, 0, stream>>>(state, Wg1, Win_n, Whh_n, bhhn, x0);
    gemm_bias_act<<<dim3(128, 8), 256, 0, stream>>>(x0, W1p, b1, xA, 1024, 288, 1);
    gemm_bias_act<<<dim3(128, 8), 256, 0, stream>>>(xA, W2b, b2, xB, 1024, 1024, 1);
    gemm_bias_act<<<dim3(128, 4), 256, 0, stream>>>(xB, W3b, b3, xA, 512, 1024, 1);
    gemm_bias_act<<<dim3(128, 2), 256, 0, stream>>>(xA, W4b, b4, xB, 256, 512, 1);
    head_kernel<<<256, 256, 0, stream>>>(xB, Wp, bp, out);
}

// Round 12
// 441.022 us; speedup vs baseline: 1.1911x; 1.1911x over previous
//
#include <hip/hip_runtime.h>

// ---------------------------------------------------------------------------
// Actor: GRU over V=20 vehicle slots (H=256) + MLP head 271->1024->1024->512->256->1
// B=16384, F=15. All GEMMs in bf16 MFMA (16x16x32), fp32 accumulate.
//
// Round-26: FINAL = r23 (session best, 445.1 us). r25's launch_bounds(512,1)
// retry confirmed the allocator law is hard: arch-VGPR cap = 65536/wg_size
// (wg-512 -> 128 ALWAYS; no attribute lifts it). Held-weight GRU needs ~220
// regs at wg-512 -> impossible; wg-256 variants are occupancy-starved at the
// mandatory 64-row/256-block grid (r21). The r11 two-pass GRU (292 us,
// 64 VGPR, 16 waves, rzbuf bounce keeping per-pass liveness at 32 regs) is
// the unique fit to all measured constraints. GEMM chain: 2-phase BK=32
// double-buffered 128x128 (r23, -15.5 us vs single-buffered).
// ---------------------------------------------------------------------------

typedef __attribute__((ext_vector_type(8))) __bf16 bf16x8;
typedef __attribute__((ext_vector_type(4))) __bf16 bf16x4;
typedef __attribute__((ext_vector_type(4))) float  floatx4;

#define MFMA16(a, b, c) __builtin_amdgcn_mfma_f32_16x16x32_bf16((a), (b), (c), 0, 0, 0)

#define GL_LDS16(g, l)                                                         \
    __builtin_amdgcn_global_load_lds(                                          \
        (const __attribute__((address_space(1))) void*)(g),                    \
        (__attribute__((address_space(3))) void*)(l), 16, 0, 0)

__device__ __forceinline__ float sigmoid_f(float x) { return 1.f / (1.f + __expf(-x)); }
__device__ __forceinline__ float tanh_f(float x)    { return 1.f - 2.f / (1.f + __expf(2.f * x)); }

// ---------------------------------------------------------------------------
// Weight prep:
//   Wg1  [512][288]  rows g in {r(0..255), z(256..511)}:
//        [W_ih[g][0..14] | bsum[g] | 0 x16 | W_hh[g][0..255]]   (col 15 = bias)
//   W1p  [1024][288] : [W1[o][0..14] | 0 x17 | W1[o][15..270]]
//   W2b  [1024][1024], W3b [512][1024], W4b [256][512]  : direct cvt
//   Win_n[256][32]   : [W_ih[512+j][0..14] | b_ih[512+j] | 0 x16] (col 15 = bias)
//   Whh_n[256][256]  : W_hh rows 512..767
//   bhhn [256] = b_hh[512+]
// ---------------------------------------------------------------------------
#define S0 147456u
#define S1 442368u
#define S2 1490944u
#define S3 2015232u
#define S4 2146304u
#define S5 2154496u
#define S6 2220032u
#define S7 2220544u
#define S8 2221056u

__global__ void prep_kernel(const float* __restrict__ W_ih, const float* __restrict__ W_hh,
                            const float* __restrict__ b_ih, const float* __restrict__ b_hh,
                            const float* __restrict__ W1, const float* __restrict__ W2,
                            const float* __restrict__ W3, const float* __restrict__ W4,
                            __bf16* __restrict__ Wg1, __bf16* __restrict__ W1p,
                            __bf16* __restrict__ W2b, __bf16* __restrict__ W3b,
                            __bf16* __restrict__ W4b, __bf16* __restrict__ Win_n,
                            __bf16* __restrict__ Whh_n, float* __restrict__ bsum,
                            float* __restrict__ bihn, float* __restrict__ bhhn)
{
    for (unsigned i = blockIdx.x * blockDim.x + threadIdx.x; i < S8; i += gridDim.x * blockDim.x) {
        if (i < S0) {
            unsigned g = i / 288u, c = i % 288u;
            float v;
            if (c < 15u)       v = W_ih[g * 15u + c];
            else if (c == 15u) v = b_ih[g] + b_hh[g];          // folded r/z bias
            else if (c < 32u)  v = 0.f;
            else               v = W_hh[g * 256u + (c - 32u)];
            Wg1[i] = (__bf16)v;
        } else if (i < S1) {
            unsigned t = i - S0, o = t / 288u, c = t % 288u;
            float v = (c < 15u) ? W1[o * 271u + c] : ((c < 32u) ? 0.f : W1[o * 271u + (c - 17u)]);
            W1p[t] = (__bf16)v;
        } else if (i < S2) {
            unsigned t = i - S1; W2b[t] = (__bf16)W2[t];
        } else if (i < S3) {
            unsigned t = i - S2; W3b[t] = (__bf16)W3[t];
        } else if (i < S4) {
            unsigned t = i - S3; W4b[t] = (__bf16)W4[t];
        } else if (i < S5) {
            unsigned t = i - S4, j = t / 32u, c = t % 32u;
            float v;
            if (c < 15u)       v = W_ih[(512u + j) * 15u + c];
            else if (c == 15u) v = b_ih[512u + j];             // folded xn bias
            else               v = 0.f;
            Win_n[t] = (__bf16)v;
        } else if (i < S6) {
            unsigned t = i - S5; Whh_n[t] = (__bf16)W_hh[512u * 256u + t];
        } else if (i < S7) {
            unsigned t = i - S6; bsum[t] = b_ih[t] + b_hh[t];
        } else {
            unsigned t = i - S7;
            if (t < 256u) bihn[t] = b_ih[512u + t];
            else          bhhn[t - 256u] = b_hh[512u + t - 256u];
        }
    }
}

// ---------------------------------------------------------------------------
// GRU kernel (r11, UNCHANGED). 256 blocks x 1024 threads (16 waves). 64 batch
// rows/block. Wave w owns gate cols w*16..w*16+15. Per step, 2 unroll-1
// passes:
//   p0: acc (ar,az) over all 4 nt (32 regs) -> sigmoid -> rzbuf[nt][tid]
//   p1: acc (axn,ahn) (32 regs) -> n=tanh(axn+r*(ahn+bhn)), h'=(1-z)n+z*h_old
// hbuf[2][64][264] double-buffered, 1 barrier/step. sbuf stride 40:
// 5*ln+q mod 8 covers all 8 bank groups -> conflict-free state reads.
// ---------------------------------------------------------------------------
#define HSTRIDE 264
#define HBUF_N  (64 * HSTRIDE)
#define SSTRIDE 40
#define SBUF_N  (64 * SSTRIDE)    // 2560 per buffer

__global__ __launch_bounds__(1024)
void gru_kernel(const float* __restrict__ state,
                const __bf16* __restrict__ Wg1,  const __bf16* __restrict__ Win_n,
                const __bf16* __restrict__ Whh_n,
                const float* __restrict__ bhhn, __bf16* __restrict__ x0)
{
    __shared__ __bf16 hbuf[2 * HBUF_N];        // 67584 B
    __shared__ __bf16 sbuf[2 * SBUF_N];        // 10240 B; k 16..39 zero, k15 = 1.0
    __shared__ __bf16 rzbuf[4 * 1024 * 8];     // 65536 B: [nt][tid][8] r0..3|z0..3

    const int tid  = threadIdx.x;
    const int wave = tid >> 6;    // 0..15 : j-tile
    const int lane = tid & 63;
    const int q    = lane >> 4;
    const int ln   = lane & 15;
    const int b0   = blockIdx.x * 64;

    {   // zero h buffer 0 and both sbuf buffers
        bf16x8 z = {};
        bf16x8* p = (bf16x8*)hbuf;
        #pragma unroll 3
        for (int i = tid; i < HBUF_N / 8; i += 1024) p[i] = z;
        if (tid < 2 * SBUF_N / 8) ((bf16x8*)sbuf)[tid] = z;
    }
    const int srow = tid >> 4, sk = tid & 15;   // 64 rows x 16 cols staging

    // bhn (other biases folded into weight col 15 against sbuf's 1.0 column)
    const floatx4 Bhn = *(const floatx4*)(bhhn + wave * 16 + q * 4);

    const int jr = wave * 16 + ln;
    const __bf16* wr = Wg1   + (size_t)jr * 288 + q * 8;
    const __bf16* wz = Wg1   + (size_t)(256 + jr) * 288 + q * 8;
    const __bf16* wx = Win_n + (size_t)jr * 32  + q * 8;
    const __bf16* wh = Whh_n + (size_t)jr * 256 + q * 8;

    const __bf16* hread  = hbuf + ln * HSTRIDE + q * 8;              // + nt*16*HSTRIDE
    __bf16*       hwrite = hbuf + ln * HSTRIDE + wave * 16 + q * 4;  // + nt*16*HSTRIDE
    const __bf16* sread  = sbuf + ln * SSTRIDE + q * 8;              // + nt*16*SSTRIDE
    __bf16*       rzw    = rzbuf + tid * 8;                          // + nt*8192

    // stage state slice v=0, then set the permanent 1.0 bias column (k=15)
    if (sk < 15)
        sbuf[srow * SSTRIDE + sk] = (__bf16)state[(size_t)(b0 + srow) * 300 + sk];
    if (tid < 128) sbuf[(tid >> 6) * SBUF_N + (tid & 63) * SSTRIDE + 15] = (__bf16)1.0f;
    __syncthreads();

#define GRU_STEP(v, SB)                                                          \
    {                                                                            \
        float snext = 0.f;                                                       \
        if ((v) < 19 && sk < 15)                                                 \
            snext = state[(size_t)(b0 + srow) * 300 + ((v) + 1) * 15 + sk];      \
        _Pragma("unroll 1")                                                      \
        for (int p = 0; p < 2; ++p) {                                            \
            floatx4 acc0[4], acc1[4];                                            \
            const floatx4 zf = {0.f, 0.f, 0.f, 0.f};                             \
            _Pragma("unroll")                                                    \
            for (int nt = 0; nt < 4; nt++) { acc0[nt] = zf; acc1[nt] = zf; }     \
            if (p == 0) {                                                        \
                {                                                                \
                    bf16x8 a0 = *(const bf16x8*)(wr);                            \
                    bf16x8 a1 = *(const bf16x8*)(wz);                            \
                    _Pragma("unroll")                                            \
                    for (int nt = 0; nt < 4; nt++) {                             \
                        bf16x8 b = *(const bf16x8*)(sread + (SB) * SBUF_N +      \
                                                    nt * (16 * SSTRIDE));        \
                        acc0[nt] = MFMA16(a0, b, acc0[nt]);                      \
                        acc1[nt] = MFMA16(a1, b, acc1[nt]);                      \
                    }                                                            \
                }                                                                \
                _Pragma("unroll")                                                \
                for (int kk = 0; kk < 8; ++kk) {                                 \
                    bf16x8 a0 = *(const bf16x8*)(wr + 32 + kk * 32);             \
                    bf16x8 a1 = *(const bf16x8*)(wz + 32 + kk * 32);             \
                    _Pragma("unroll")                                            \
                    for (int nt = 0; nt < 4; nt++) {                             \
                        bf16x8 b = *(const bf16x8*)(hread + (SB) * HBUF_N +      \
                                                    nt * (16 * HSTRIDE) +        \
                                                    kk * 32);                    \
                        acc0[nt] = MFMA16(a0, b, acc0[nt]);                      \
                        acc1[nt] = MFMA16(a1, b, acc1[nt]);                      \
                    }                                                            \
                }                                                                \
                _Pragma("unroll")                                                \
                for (int nt = 0; nt < 4; nt++) {                                 \
                    bf16x8 rz;                                                   \
                    _Pragma("unroll")                                            \
                    for (int r = 0; r < 4; r++) {                                \
                        rz[r]     = (__bf16)sigmoid_f(acc0[nt][r]);              \
                        rz[4 + r] = (__bf16)sigmoid_f(acc1[nt][r]);              \
                    }                                                            \
                    *(bf16x8*)(rzw + nt * 8192) = rz;                            \
                }                                                                \
            } else {                                                             \
                {                                                                \
                    bf16x8 a0 = *(const bf16x8*)(wx);                            \
                    _Pragma("unroll")                                            \
                    for (int nt = 0; nt < 4; nt++) {                             \
                        bf16x8 b = *(const bf16x8*)(sread + (SB) * SBUF_N +      \
                                                    nt * (16 * SSTRIDE));        \
                        acc0[nt] = MFMA16(a0, b, acc0[nt]);                      \
                    }                                                            \
                }                                                                \
                _Pragma("unroll")                                                \
                for (int kk = 0; kk < 8; ++kk) {                                 \
                    bf16x8 a1 = *(const bf16x8*)(wh + kk * 32);                  \
                    _Pragma("unroll")                                            \
                    for (int nt = 0; nt < 4; nt++) {                             \
                        bf16x8 b = *(const bf16x8*)(hread + (SB) * HBUF_N +      \
                                                    nt * (16 * HSTRIDE) +        \
                                                    kk * 32);                    \
                        acc1[nt] = MFMA16(a1, b, acc1[nt]);                      \
                    }                                                            \
                }                                                                \
                _Pragma("unroll")                                                \
                for (int nt = 0; nt < 4; nt++) {                                 \
                    bf16x8 rz = *(const bf16x8*)(rzw + nt * 8192);               \
                    bf16x4 ho = *(const bf16x4*)(hwrite + (SB) * HBUF_N +        \
                                                 nt * (16 * HSTRIDE));           \
                    bf16x4 hv;                                                   \
                    _Pragma("unroll")                                            \
                    for (int r = 0; r < 4; r++) {                                \
                        float rg = (float)rz[r];                                 \
                        float zg = (float)rz[4 + r];                             \
                        float nn = tanh_f(acc0[nt][r] +                          \
                                          rg * (acc1[nt][r] + Bhn[r]));          \
                        float hnew = (1.f - zg) * nn + zg * (float)ho[r];        \
                        hv[r] = (__bf16)hnew;                                    \
                    }                                                            \
                    *(bf16x4*)(hwrite + (1 - (SB)) * HBUF_N +                    \
                               nt * (16 * HSTRIDE)) = hv;                        \
                }                                                                \
            }                                                                    \
        }                                                                        \
        if ((v) < 19 && sk < 15)                                                 \
            sbuf[(1 - (SB)) * SBUF_N + srow * SSTRIDE + sk] = (__bf16)snext;     \
        __syncthreads();                                                         \
    }

    #pragma unroll 1
    for (int v2 = 0; v2 < 10; ++v2) {
        GRU_STEP(2 * v2,     0)
        GRU_STEP(2 * v2 + 1, 1)
    }
#undef GRU_STEP

    // ---- epilogue: final h is in hbuf buffer 0 (step 19 wrote 1-SB = 0) ----
    // x0 = [state[:,0,:] (15) | 0-pad to 32 | h (256)], coalesced b128 moves.
    {
        const int erow = tid >> 4, p = tid & 15;
        #pragma unroll
        for (int s = 0; s < 2; s++) {
            const int col = p * 8 + s * 128;
            *(bf16x8*)(x0 + (size_t)(b0 + erow) * 288 + 32 + col) =
                *(const bf16x8*)(hbuf + erow * HSTRIDE + col);
        }
    }
    #pragma unroll
    for (int t = 0; t < 2; t++) {
        int i = tid + t * 1024;
        int erow = i >> 5, c = i & 31;
        float s = (c < 15) ? state[(size_t)(b0 + erow) * 300 + c] : 0.f;
        x0[(size_t)(b0 + erow) * 288 + c] = (__bf16)s;
    }
}

// ---------------------------------------------------------------------------
// LDS-staged GEMM, BK=32 double-buffered (T3 minimum 2-phase):
// C = act(A[M][K] @ W[N][K]^T + bias), bf16. 256 thr (4 waves 2x2), tile
// 128x128. Loads for slab k+1 issued AFTER the barrier and BEFORE compute
// of slab k -> the vmcnt(0) drain at the next barrier lands one compute
// phase later. Staging 32KB inside the 34.8KB bounce union (4 blocks/CU).
// ---------------------------------------------------------------------------
__global__ __launch_bounds__(256)
void gemm_bias_act(const __bf16* __restrict__ A, const __bf16* __restrict__ W,
                   const float* __restrict__ bias, __bf16* __restrict__ C,
                   int N, int K, int relu)
{
    __shared__ __bf16 smem[128 * 136];           // 34816 B (bounce; staging in first 32KB)
    // staging (bf16 units): buf0 A @0, B @4096; buf1 A @8192, B @12288

    const int tid  = threadIdx.x;
    const int wave = tid >> 6, lane = tid & 63;
    const int q = lane >> 4, ln = lane & 15;
    const int wm = wave >> 1, wn = wave & 1;
    const int arow0 = blockIdx.x * 128;
    const int bcol0 = blockIdx.y * 128;

    float bv[4];
    #pragma unroll
    for (int n = 0; n < 4; n++) bv[n] = bias[bcol0 + wn * 64 + n * 16 + ln];

    floatx4 acc[4][4];
    const floatx4 zf = {0.f, 0.f, 0.f, 0.f};
    #pragma unroll
    for (int m = 0; m < 4; m++)
        #pragma unroll
        for (int n = 0; n < 4; n++) acc[m][n] = zf;

    const int stg_row = wave * 16 + (lane >> 2);   // + rd*64
    const int stg_k   = (lane & 3) * 8;
    const int lds_off = wave * 512;                // + rd*2048

#define STAGE(kt, b)                                                            \
    {                                                                           \
        _Pragma("unroll")                                                       \
        for (int rd = 0; rd < 2; rd++) {                                        \
            GL_LDS16(A + (size_t)(arow0 + stg_row + rd * 64) * K + (kt) * 32 + stg_k, \
                     smem + (b) * 8192 + lds_off + rd * 2048);                  \
            GL_LDS16(W + (size_t)(bcol0 + stg_row + rd * 64) * K + (kt) * 32 + stg_k, \
                     smem + 4096 + (b) * 8192 + lds_off + rd * 2048);           \
        }                                                                       \
    }

#define GCOMPUTE(b)                                                             \
    {                                                                           \
        bf16x8 af[4], bf[4];                                                    \
        _Pragma("unroll")                                                       \
        for (int m = 0; m < 4; m++)                                             \
            af[m] = *(const bf16x8*)(smem + (b) * 8192 +                        \
                                     (wm * 64 + m * 16 + ln) * 32 + q * 8);     \
        _Pragma("unroll")                                                       \
        for (int n = 0; n < 4; n++)                                             \
            bf[n] = *(const bf16x8*)(smem + 4096 + (b) * 8192 +                 \
                                     (wn * 64 + n * 16 + ln) * 32 + q * 8);     \
        _Pragma("unroll")                                                       \
        for (int n = 0; n < 4; n++)                                             \
            _Pragma("unroll")                                                   \
            for (int m = 0; m < 4; m++)                                         \
                acc[m][n] = MFMA16(af[m], bf[n], acc[m][n]);                    \
    }

    const int nk = K >> 5;          // K multiple of 32 for all layers
    STAGE(0, 0)
    int kt = 0;
    #pragma unroll 1
    for (; kt + 2 <= nk; kt += 2) {
        __syncthreads();                 // buf0 slab ready; buf1 free
        if (kt + 1 < nk) STAGE(kt + 1, 1)
        GCOMPUTE(0)                      // compute slab kt while kt+1 loads fly
        __syncthreads();                 // buf1 slab ready; buf0 free
        if (kt + 2 < nk) STAGE(kt + 2, 0)
        GCOMPUTE(1)                      // compute slab kt+1 while kt+2 loads fly
    }
    if (kt < nk) {                       // odd slab count (gemm1: nk=9)
        __syncthreads();
        GCOMPUTE(0)
    }
    __syncthreads();                     // staging reads done -> bounce may reuse
#undef STAGE
#undef GCOMPUTE

    // epilogue: bias+act -> LDS bounce (stride 136) -> coalesced b128 stores
    #pragma unroll
    for (int m = 0; m < 4; m++)
        #pragma unroll
        for (int n = 0; n < 4; n++)
            #pragma unroll
            for (int r = 0; r < 4; r++) {
                float val = acc[m][n][r] + bv[n];
                if (relu) val = fmaxf(val, 0.f);
                smem[(wm * 64 + m * 16 + q * 4 + r) * 136 + wn * 64 + n * 16 + ln] = (__bf16)val;
            }
    __syncthreads();
    {
        const int row = tid >> 4, seg = tid & 15;
        #pragma unroll
        for (int p = 0; p < 8; p++) {
            const int rr = row + p * 16;
            *(bf16x8*)(C + (size_t)(arow0 + rr) * N + bcol0 + seg * 8) =
                *(const bf16x8*)(smem + rr * 136 + seg * 8);
        }
    }
}

// ---------------------------------------------------------------------------
// Head: out[b] = tanh(dot(x4[b][0..255], Wp) + bp).  4 lanes per row.
// ---------------------------------------------------------------------------
__global__ __launch_bounds__(256)
void head_kernel(const __bf16* __restrict__ x4, const float* __restrict__ Wp,
                 const float* __restrict__ bp, float* __restrict__ out)
{
    const int tid = threadIdx.x;
    const int wave = tid >> 6, lane = tid & 63;
    const int row = blockIdx.x * 64 + wave * 16 + (lane >> 2);
    const int part = lane & 3;
    const __bf16* xp = x4 + (size_t)row * 256 + part * 64;
    const float* wp = Wp + part * 64;
    float sum = 0.f;
    #pragma unroll
    for (int i = 0; i < 8; i++) {
        bf16x8 xv = *(const bf16x8*)(xp + i * 8);
        #pragma unroll
        for (int jj = 0; jj < 8; jj++) sum += (float)xv[jj] * wp[i * 8 + jj];
    }
    sum += __shfl_xor(sum, 1);
    sum += __shfl_xor(sum, 2);
    if (part == 0) out[row] = tanhf(sum + bp[0]);
}

// ---------------------------------------------------------------------------
extern "C" void kernel_launch(void* const* d_in, const int* in_sizes, int n_in,
                              void* d_out, int out_size, void* d_ws, size_t ws_size,
                              hipStream_t stream)
{
    const float* state = (const float*)d_in[0];
    const float* W_ih  = (const float*)d_in[1];
    const float* W_hh  = (const float*)d_in[2];
    const float* b_ih  = (const float*)d_in[3];
    const float* b_hh  = (const float*)d_in[4];
    const float* W1    = (const float*)d_in[5];
    const float* b1    = (const float*)d_in[6];
    const float* W2    = (const float*)d_in[7];
    const float* b2    = (const float*)d_in[8];
    const float* W3    = (const float*)d_in[9];
    const float* b3    = (const float*)d_in[10];
    const float* W4    = (const float*)d_in[11];
    const float* b4    = (const float*)d_in[12];
    const float* Wp    = (const float*)d_in[13];
    const float* bp    = (const float*)d_in[14];
    float* out = (float*)d_out;

    char* ws = (char*)d_ws;
    size_t off = 0;
    auto alloc = [&](size_t bytes) -> void* {
        void* p = ws + off;
        off += (bytes + 255) & ~(size_t)255;
        return p;
    };
    __bf16* Wg1   = (__bf16*)alloc(512 * 288 * 2);
    __bf16* W1p   = (__bf16*)alloc(1024 * 288 * 2);
    __bf16* W2b   = (__bf16*)alloc(1024 * 1024 * 2);
    __bf16* W3b   = (__bf16*)alloc(512 * 1024 * 2);
    __bf16* W4b   = (__bf16*)alloc(256 * 512 * 2);
    __bf16* Win_n = (__bf16*)alloc(256 * 32 * 2);
    __bf16* Whh_n = (__bf16*)alloc(256 * 256 * 2);
    float*  bsum  = (float*)alloc(512 * 4);
    float*  bihn  = (float*)alloc(256 * 4);
    float*  bhhn  = (float*)alloc(256 * 4);
    __bf16* x0    = (__bf16*)alloc((size_t)16384 * 288 * 2);
    __bf16* xA    = (__bf16*)alloc((size_t)16384 * 1024 * 2);
    __bf16* xB    = (__bf16*)alloc((size_t)16384 * 1024 * 2);

    prep_kernel<<<2048, 256, 0, stream>>>(W_ih, W_hh, b_ih, b_hh, W1, W2, W3, W4,
                                          Wg1, W1p, W2b, W3b, W4b, Win_n, Whh_n,
                                          bsum, bihn, bhhn);
    gru_kernel<<<256, 1024, 0, stream>>>(state, Wg1, Win_n, Whh_n, bhhn, x0);
    gemm_bias_act<<<dim3(128, 8), 256, 0, stream>>>(x0, W1p, b1, xA, 1024, 288, 1);
    gemm_bias_act<<<dim3(128, 8), 256, 0, stream>>>(xA, W2b, b2, xB, 1024, 1024, 1);
    gemm_bias_act<<<dim3(128, 4), 256, 0, stream>>>(xB, W3b, b3, xA, 512, 1024, 1);
    gemm_bias_act<<<dim3(128, 2), 256, 0, stream>>>(xA, W4b, b4, xB, 256, 512, 1);
    head_kernel<<<256, 256, 0, stream>>>(xB, Wp, bp, out);
}

// Round 13
// 433.835 us; speedup vs baseline: 1.2108x; 1.0166x over previous
//
#include <hip/hip_runtime.h>

// ---------------------------------------------------------------------------
// Actor: GRU over V=20 vehicle slots (H=256) + MLP head 271->1024->1024->512->256->1
// B=16384, F=15. All GEMMs in bf16 MFMA (16x16x32), fp32 accumulate.
//
// Round-27: GRU untouched (r11, 292 us, boxed by the allocator laws). GEMM
// K-loop upgraded from __syncthreads 2-phase (depth-1: every __syncthreads
// drains vmcnt(0)) to a 2-deep counted-vmcnt pipeline (T3+T4): raw
// s_barrier + s_waitcnt vmcnt(4) keeps slab k+2's global_load_lds in flight
// across barriers. Per slab: vmcnt(4) -> barrier -> frag ds_reads ->
// lgkmcnt(0)+sched_barrier -> barrier (all waves done reading buf b) ->
// STAGE(k+2,b) -> MFMA. Buffer overwrite only after the all-read barrier;
// vmcnt FIFO (m135) makes the oldest slab complete first. Same 32KB staging
// union, 4 blocks/CU.
// ---------------------------------------------------------------------------

typedef __attribute__((ext_vector_type(8))) __bf16 bf16x8;
typedef __attribute__((ext_vector_type(4))) __bf16 bf16x4;
typedef __attribute__((ext_vector_type(4))) float  floatx4;

#define MFMA16(a, b, c) __builtin_amdgcn_mfma_f32_16x16x32_bf16((a), (b), (c), 0, 0, 0)

#define GL_LDS16(g, l)                                                         \
    __builtin_amdgcn_global_load_lds(                                          \
        (const __attribute__((address_space(1))) void*)(g),                    \
        (__attribute__((address_space(3))) void*)(l), 16, 0, 0)

__device__ __forceinline__ float sigmoid_f(float x) { return 1.f / (1.f + __expf(-x)); }
__device__ __forceinline__ float tanh_f(float x)    { return 1.f - 2.f / (1.f + __expf(2.f * x)); }

// ---------------------------------------------------------------------------
// Weight prep:
//   Wg1  [512][288]  rows g in {r(0..255), z(256..511)}:
//        [W_ih[g][0..14] | bsum[g] | 0 x16 | W_hh[g][0..255]]   (col 15 = bias)
//   W1p  [1024][288] : [W1[o][0..14] | 0 x17 | W1[o][15..270]]
//   W2b  [1024][1024], W3b [512][1024], W4b [256][512]  : direct cvt
//   Win_n[256][32]   : [W_ih[512+j][0..14] | b_ih[512+j] | 0 x16] (col 15 = bias)
//   Whh_n[256][256]  : W_hh rows 512..767
//   bhhn [256] = b_hh[512+]
// ---------------------------------------------------------------------------
#define S0 147456u
#define S1 442368u
#define S2 1490944u
#define S3 2015232u
#define S4 2146304u
#define S5 2154496u
#define S6 2220032u
#define S7 2220544u
#define S8 2221056u

__global__ void prep_kernel(const float* __restrict__ W_ih, const float* __restrict__ W_hh,
                            const float* __restrict__ b_ih, const float* __restrict__ b_hh,
                            const float* __restrict__ W1, const float* __restrict__ W2,
                            const float* __restrict__ W3, const float* __restrict__ W4,
                            __bf16* __restrict__ Wg1, __bf16* __restrict__ W1p,
                            __bf16* __restrict__ W2b, __bf16* __restrict__ W3b,
                            __bf16* __restrict__ W4b, __bf16* __restrict__ Win_n,
                            __bf16* __restrict__ Whh_n, float* __restrict__ bsum,
                            float* __restrict__ bihn, float* __restrict__ bhhn)
{
    for (unsigned i = blockIdx.x * blockDim.x + threadIdx.x; i < S8; i += gridDim.x * blockDim.x) {
        if (i < S0) {
            unsigned g = i / 288u, c = i % 288u;
            float v;
            if (c < 15u)       v = W_ih[g * 15u + c];
            else if (c == 15u) v = b_ih[g] + b_hh[g];          // folded r/z bias
            else if (c < 32u)  v = 0.f;
            else               v = W_hh[g * 256u + (c - 32u)];
            Wg1[i] = (__bf16)v;
        } else if (i < S1) {
            unsigned t = i - S0, o = t / 288u, c = t % 288u;
            float v = (c < 15u) ? W1[o * 271u + c] : ((c < 32u) ? 0.f : W1[o * 271u + (c - 17u)]);
            W1p[t] = (__bf16)v;
        } else if (i < S2) {
            unsigned t = i - S1; W2b[t] = (__bf16)W2[t];
        } else if (i < S3) {
            unsigned t = i - S2; W3b[t] = (__bf16)W3[t];
        } else if (i < S4) {
            unsigned t = i - S3; W4b[t] = (__bf16)W4[t];
        } else if (i < S5) {
            unsigned t = i - S4, j = t / 32u, c = t % 32u;
            float v;
            if (c < 15u)       v = W_ih[(512u + j) * 15u + c];
            else if (c == 15u) v = b_ih[512u + j];             // folded xn bias
            else               v = 0.f;
            Win_n[t] = (__bf16)v;
        } else if (i < S6) {
            unsigned t = i - S5; Whh_n[t] = (__bf16)W_hh[512u * 256u + t];
        } else if (i < S7) {
            unsigned t = i - S6; bsum[t] = b_ih[t] + b_hh[t];
        } else {
            unsigned t = i - S7;
            if (t < 256u) bihn[t] = b_ih[512u + t];
            else          bhhn[t - 256u] = b_hh[512u + t - 256u];
        }
    }
}

// ---------------------------------------------------------------------------
// GRU kernel (r11, UNCHANGED). 256 blocks x 1024 threads (16 waves). 64 batch
// rows/block. Wave w owns gate cols w*16..w*16+15. Per step, 2 unroll-1
// passes:
//   p0: acc (ar,az) over all 4 nt (32 regs) -> sigmoid -> rzbuf[nt][tid]
//   p1: acc (axn,ahn) (32 regs) -> n=tanh(axn+r*(ahn+bhn)), h'=(1-z)n+z*h_old
// hbuf[2][64][264] double-buffered, 1 barrier/step. sbuf stride 40:
// 5*ln+q mod 8 covers all 8 bank groups -> conflict-free state reads.
// ---------------------------------------------------------------------------
#define HSTRIDE 264
#define HBUF_N  (64 * HSTRIDE)
#define SSTRIDE 40
#define SBUF_N  (64 * SSTRIDE)    // 2560 per buffer

__global__ __launch_bounds__(1024)
void gru_kernel(const float* __restrict__ state,
                const __bf16* __restrict__ Wg1,  const __bf16* __restrict__ Win_n,
                const __bf16* __restrict__ Whh_n,
                const float* __restrict__ bhhn, __bf16* __restrict__ x0)
{
    __shared__ __bf16 hbuf[2 * HBUF_N];        // 67584 B
    __shared__ __bf16 sbuf[2 * SBUF_N];        // 10240 B; k 16..39 zero, k15 = 1.0
    __shared__ __bf16 rzbuf[4 * 1024 * 8];     // 65536 B: [nt][tid][8] r0..3|z0..3

    const int tid  = threadIdx.x;
    const int wave = tid >> 6;    // 0..15 : j-tile
    const int lane = tid & 63;
    const int q    = lane >> 4;
    const int ln   = lane & 15;
    const int b0   = blockIdx.x * 64;

    {   // zero h buffer 0 and both sbuf buffers
        bf16x8 z = {};
        bf16x8* p = (bf16x8*)hbuf;
        #pragma unroll 3
        for (int i = tid; i < HBUF_N / 8; i += 1024) p[i] = z;
        if (tid < 2 * SBUF_N / 8) ((bf16x8*)sbuf)[tid] = z;
    }
    const int srow = tid >> 4, sk = tid & 15;   // 64 rows x 16 cols staging

    // bhn (other biases folded into weight col 15 against sbuf's 1.0 column)
    const floatx4 Bhn = *(const floatx4*)(bhhn + wave * 16 + q * 4);

    const int jr = wave * 16 + ln;
    const __bf16* wr = Wg1   + (size_t)jr * 288 + q * 8;
    const __bf16* wz = Wg1   + (size_t)(256 + jr) * 288 + q * 8;
    const __bf16* wx = Win_n + (size_t)jr * 32  + q * 8;
    const __bf16* wh = Whh_n + (size_t)jr * 256 + q * 8;

    const __bf16* hread  = hbuf + ln * HSTRIDE + q * 8;              // + nt*16*HSTRIDE
    __bf16*       hwrite = hbuf + ln * HSTRIDE + wave * 16 + q * 4;  // + nt*16*HSTRIDE
    const __bf16* sread  = sbuf + ln * SSTRIDE + q * 8;              // + nt*16*SSTRIDE
    __bf16*       rzw    = rzbuf + tid * 8;                          // + nt*8192

    // stage state slice v=0, then set the permanent 1.0 bias column (k=15)
    if (sk < 15)
        sbuf[srow * SSTRIDE + sk] = (__bf16)state[(size_t)(b0 + srow) * 300 + sk];
    if (tid < 128) sbuf[(tid >> 6) * SBUF_N + (tid & 63) * SSTRIDE + 15] = (__bf16)1.0f;
    __syncthreads();

#define GRU_STEP(v, SB)                                                          \
    {                                                                            \
        float snext = 0.f;                                                       \
        if ((v) < 19 && sk < 15)                                                 \
            snext = state[(size_t)(b0 + srow) * 300 + ((v) + 1) * 15 + sk];      \
        _Pragma("unroll 1")                                                      \
        for (int p = 0; p < 2; ++p) {                                            \
            floatx4 acc0[4], acc1[4];                                            \
            const floatx4 zf = {0.f, 0.f, 0.f, 0.f};                             \
            _Pragma("unroll")                                                    \
            for (int nt = 0; nt < 4; nt++) { acc0[nt] = zf; acc1[nt] = zf; }     \
            if (p == 0) {                                                        \
                {                                                                \
                    bf16x8 a0 = *(const bf16x8*)(wr);                            \
                    bf16x8 a1 = *(const bf16x8*)(wz);                            \
                    _Pragma("unroll")                                            \
                    for (int nt = 0; nt < 4; nt++) {                             \
                        bf16x8 b = *(const bf16x8*)(sread + (SB) * SBUF_N +      \
                                                    nt * (16 * SSTRIDE));        \
                        acc0[nt] = MFMA16(a0, b, acc0[nt]);                      \
                        acc1[nt] = MFMA16(a1, b, acc1[nt]);                      \
                    }                                                            \
                }                                                                \
                _Pragma("unroll")                                                \
                for (int kk = 0; kk < 8; ++kk) {                                 \
                    bf16x8 a0 = *(const bf16x8*)(wr + 32 + kk * 32);             \
                    bf16x8 a1 = *(const bf16x8*)(wz + 32 + kk * 32);             \
                    _Pragma("unroll")                                            \
                    for (int nt = 0; nt < 4; nt++) {                             \
                        bf16x8 b = *(const bf16x8*)(hread + (SB) * HBUF_N +      \
                                                    nt * (16 * HSTRIDE) +        \
                                                    kk * 32);                    \
                        acc0[nt] = MFMA16(a0, b, acc0[nt]);                      \
                        acc1[nt] = MFMA16(a1, b, acc1[nt]);                      \
                    }                                                            \
                }                                                                \
                _Pragma("unroll")                                                \
                for (int nt = 0; nt < 4; nt++) {                                 \
                    bf16x8 rz;                                                   \
                    _Pragma("unroll")                                            \
                    for (int r = 0; r < 4; r++) {                                \
                        rz[r]     = (__bf16)sigmoid_f(acc0[nt][r]);              \
                        rz[4 + r] = (__bf16)sigmoid_f(acc1[nt][r]);              \
                    }                                                            \
                    *(bf16x8*)(rzw + nt * 8192) = rz;                            \
                }                                                                \
            } else {                                                             \
                {                                                                \
                    bf16x8 a0 = *(const bf16x8*)(wx);                            \
                    _Pragma("unroll")                                            \
                    for (int nt = 0; nt < 4; nt++) {                             \
                        bf16x8 b = *(const bf16x8*)(sread + (SB) * SBUF_N +      \
                                                    nt * (16 * SSTRIDE));        \
                        acc0[nt] = MFMA16(a0, b, acc0[nt]);                      \
                    }                                                            \
                }                                                                \
                _Pragma("unroll")                                                \
                for (int kk = 0; kk < 8; ++kk) {                                 \
                    bf16x8 a1 = *(const bf16x8*)(wh + kk * 32);                  \
                    _Pragma("unroll")                                            \
                    for (int nt = 0; nt < 4; nt++) {                             \
                        bf16x8 b = *(const bf16x8*)(hread + (SB) * HBUF_N +      \
                                                    nt * (16 * HSTRIDE) +        \
                                                    kk * 32);                    \
                        acc1[nt] = MFMA16(a1, b, acc1[nt]);                      \
                    }                                                            \
                }                                                                \
                _Pragma("unroll")                                                \
                for (int nt = 0; nt < 4; nt++) {                                 \
                    bf16x8 rz = *(const bf16x8*)(rzw + nt * 8192);               \
                    bf16x4 ho = *(const bf16x4*)(hwrite + (SB) * HBUF_N +        \
                                                 nt * (16 * HSTRIDE));           \
                    bf16x4 hv;                                                   \
                    _Pragma("unroll")                                            \
                    for (int r = 0; r < 4; r++) {                                \
                        float rg = (float)rz[r];                                 \
                        float zg = (float)rz[4 + r];                             \
                        float nn = tanh_f(acc0[nt][r] +                          \
                                          rg * (acc1[nt][r] + Bhn[r]));          \
                        float hnew = (1.f - zg) * nn + zg * (float)ho[r];        \
                        hv[r] = (__bf16)hnew;                                    \
                    }                                                            \
                    *(bf16x4*)(hwrite + (1 - (SB)) * HBUF_N +                    \
                               nt * (16 * HSTRIDE)) = hv;                        \
                }                                                                \
            }                                                                    \
        }                                                                        \
        if ((v) < 19 && sk < 15)                                                 \
            sbuf[(1 - (SB)) * SBUF_N + srow * SSTRIDE + sk] = (__bf16)snext;     \
        __syncthreads();                                                         \
    }

    #pragma unroll 1
    for (int v2 = 0; v2 < 10; ++v2) {
        GRU_STEP(2 * v2,     0)
        GRU_STEP(2 * v2 + 1, 1)
    }
#undef GRU_STEP

    // ---- epilogue: final h is in hbuf buffer 0 (step 19 wrote 1-SB = 0) ----
    // x0 = [state[:,0,:] (15) | 0-pad to 32 | h (256)], coalesced b128 moves.
    {
        const int erow = tid >> 4, p = tid & 15;
        #pragma unroll
        for (int s = 0; s < 2; s++) {
            const int col = p * 8 + s * 128;
            *(bf16x8*)(x0 + (size_t)(b0 + erow) * 288 + 32 + col) =
                *(const bf16x8*)(hbuf + erow * HSTRIDE + col);
        }
    }
    #pragma unroll
    for (int t = 0; t < 2; t++) {
        int i = tid + t * 1024;
        int erow = i >> 5, c = i & 31;
        float s = (c < 15) ? state[(size_t)(b0 + erow) * 300 + c] : 0.f;
        x0[(size_t)(b0 + erow) * 288 + c] = (__bf16)s;
    }
}

// ---------------------------------------------------------------------------
// LDS-staged GEMM, BK=32, 2-deep counted-vmcnt pipeline (T3+T4):
// C = act(A[M][K] @ W[N][K]^T + bias), bf16. 256 thr (4 waves 2x2), tile
// 128x128. Raw s_barrier + s_waitcnt vmcnt(4) keep TWO slabs of
// global_load_lds in flight (a __syncthreads would drain vmcnt(0)).
// Per slab: vmcnt(4) [slab k landed, k+1 flying] -> barrier -> frag
// ds_reads -> lgkmcnt(0)+sched_barrier -> barrier [all waves read buf b]
// -> STAGE(k+2,b) -> MFMA. Buffers only overwritten after the all-read
// barrier. Staging 32KB in the 34.8KB bounce union (4 blocks/CU).
// ---------------------------------------------------------------------------
__global__ __launch_bounds__(256)
void gemm_bias_act(const __bf16* __restrict__ A, const __bf16* __restrict__ W,
                   const float* __restrict__ bias, __bf16* __restrict__ C,
                   int N, int K, int relu)
{
    __shared__ __bf16 smem[128 * 136];           // 34816 B (bounce; staging in first 32KB)
    // staging (bf16 units): buf0 A @0, B @4096; buf1 A @8192, B @12288

    const int tid  = threadIdx.x;
    const int wave = tid >> 6, lane = tid & 63;
    const int q = lane >> 4, ln = lane & 15;
    const int wm = wave >> 1, wn = wave & 1;
    const int arow0 = blockIdx.x * 128;
    const int bcol0 = blockIdx.y * 128;

    float bv[4];
    #pragma unroll
    for (int n = 0; n < 4; n++) bv[n] = bias[bcol0 + wn * 64 + n * 16 + ln];

    floatx4 acc[4][4];
    const floatx4 zf = {0.f, 0.f, 0.f, 0.f};
    #pragma unroll
    for (int m = 0; m < 4; m++)
        #pragma unroll
        for (int n = 0; n < 4; n++) acc[m][n] = zf;

    const int stg_row = wave * 16 + (lane >> 2);   // + rd*64
    const int stg_k   = (lane & 3) * 8;
    const int lds_off = wave * 512;                // + rd*2048

#define STAGE(kt, b)                                                            \
    {                                                                           \
        _Pragma("unroll")                                                       \
        for (int rd = 0; rd < 2; rd++) {                                        \
            GL_LDS16(A + (size_t)(arow0 + stg_row + rd * 64) * K + (kt) * 32 + stg_k, \
                     smem + (b) * 8192 + lds_off + rd * 2048);                  \
            GL_LDS16(W + (size_t)(bcol0 + stg_row + rd * 64) * K + (kt) * 32 + stg_k, \
                     smem + 4096 + (b) * 8192 + lds_off + rd * 2048);           \
        }                                                                       \
    }

#define FRAG_READ(b)                                                            \
    {                                                                           \
        _Pragma("unroll")                                                       \
        for (int m = 0; m < 4; m++)                                             \
            af[m] = *(const bf16x8*)(smem + (b) * 8192 +                        \
                                     (wm * 64 + m * 16 + ln) * 32 + q * 8);     \
        _Pragma("unroll")                                                       \
        for (int n = 0; n < 4; n++)                                             \
            bf[n] = *(const bf16x8*)(smem + 4096 + (b) * 8192 +                 \
                                     (wn * 64 + n * 16 + ln) * 32 + q * 8);     \
    }

#define FRAG_MFMA                                                               \
    {                                                                           \
        _Pragma("unroll")                                                       \
        for (int n = 0; n < 4; n++)                                             \
            _Pragma("unroll")                                                   \
            for (int m = 0; m < 4; m++)                                         \
                acc[m][n] = MFMA16(af[m], bf[n], acc[m][n]);                    \
    }

    const int nk = K >> 5;          // K multiple of 32 for all layers (nk >= 9)
    STAGE(0, 0)
    STAGE(1, 1)
    bf16x8 af[4], bf[4];
    int k = 0;
    #pragma unroll 1
    for (; k + 2 < nk; ++k) {
        const int b = k & 1;
        asm volatile("s_waitcnt vmcnt(4)" ::: "memory");   // slab k landed; k+1 flying
        __builtin_amdgcn_s_barrier();                      // all waves' slab-k writes visible
        asm volatile("" ::: "memory");
        FRAG_READ(b)
        asm volatile("s_waitcnt lgkmcnt(0)" ::: "memory"); // my reads of buf b done
        __builtin_amdgcn_sched_barrier(0);                 // rule #18: pin MFMAs below
        __builtin_amdgcn_s_barrier();                      // ALL waves done reading buf b
        asm volatile("" ::: "memory");
        STAGE(k + 2, b)                                    // safe overwrite; 2 slabs in flight
        FRAG_MFMA
    }
    {   // k == nk-2: slab nk-1 still flying, no further staging
        const int b = (nk - 2) & 1;
        asm volatile("s_waitcnt vmcnt(4)" ::: "memory");
        __builtin_amdgcn_s_barrier();
        asm volatile("" ::: "memory");
        FRAG_READ(b)
        FRAG_MFMA
    }
    {   // k == nk-1: drain everything
        const int b = (nk - 1) & 1;
        asm volatile("s_waitcnt vmcnt(0)" ::: "memory");
        __builtin_amdgcn_s_barrier();
        asm volatile("" ::: "memory");
        FRAG_READ(b)
        FRAG_MFMA
    }
    __syncthreads();                     // staging reads done -> bounce may reuse
#undef STAGE
#undef FRAG_READ
#undef FRAG_MFMA

    // epilogue: bias+act -> LDS bounce (stride 136) -> coalesced b128 stores
    #pragma unroll
    for (int m = 0; m < 4; m++)
        #pragma unroll
        for (int n = 0; n < 4; n++)
            #pragma unroll
            for (int r = 0; r < 4; r++) {
                float val = acc[m][n][r] + bv[n];
                if (relu) val = fmaxf(val, 0.f);
                smem[(wm * 64 + m * 16 + q * 4 + r) * 136 + wn * 64 + n * 16 + ln] = (__bf16)val;
            }
    __syncthreads();
    {
        const int row = tid >> 4, seg = tid & 15;
        #pragma unroll
        for (int p = 0; p < 8; p++) {
            const int rr = row + p * 16;
            *(bf16x8*)(C + (size_t)(arow0 + rr) * N + bcol0 + seg * 8) =
                *(const bf16x8*)(smem + rr * 136 + seg * 8);
        }
    }
}

// ---------------------------------------------------------------------------
// Head: out[b] = tanh(dot(x4[b][0..255], Wp) + bp).  4 lanes per row.
// ---------------------------------------------------------------------------
__global__ __launch_bounds__(256)
void head_kernel(const __bf16* __restrict__ x4, const float* __restrict__ Wp,
                 const float* __restrict__ bp, float* __restrict__ out)
{
    const int tid = threadIdx.x;
    const int wave = tid >> 6, lane = tid & 63;
    const int row = blockIdx.x * 64 + wave * 16 + (lane >> 2);
    const int part = lane & 3;
    const __bf16* xp = x4 + (size_t)row * 256 + part * 64;
    const float* wp = Wp + part * 64;
    float sum = 0.f;
    #pragma unroll
    for (int i = 0; i < 8; i++) {
        bf16x8 xv = *(const bf16x8*)(xp + i * 8);
        #pragma unroll
        for (int jj = 0; jj < 8; jj++) sum += (float)xv[jj] * wp[i * 8 + jj];
    }
    sum += __shfl_xor(sum, 1);
    sum += __shfl_xor(sum, 2);
    if (part == 0) out[row] = tanhf(sum + bp[0]);
}

// ---------------------------------------------------------------------------
extern "C" void kernel_launch(void* const* d_in, const int* in_sizes, int n_in,
                              void* d_out, int out_size, void* d_ws, size_t ws_size,
                              hipStream_t stream)
{
    const float* state = (const float*)d_in[0];
    const float* W_ih  = (const float*)d_in[1];
    const float* W_hh  = (const float*)d_in[2];
    const float* b_ih  = (const float*)d_in[3];
    const float* b_hh  = (const float*)d_in[4];
    const float* W1    = (const float*)d_in[5];
    const float* b1    = (const float*)d_in[6];
    const float* W2    = (const float*)d_in[7];
    const float* b2    = (const float*)d_in[8];
    const float* W3    = (const float*)d_in[9];
    const float* b3    = (const float*)d_in[10];
    const float* W4    = (const float*)d_in[11];
    const float* b4    = (const float*)d_in[12];
    const float* Wp    = (const float*)d_in[13];
    const float* bp    = (const float*)d_in[14];
    float* out = (float*)d_out;

    char* ws = (char*)d_ws;
    size_t off = 0;
    auto alloc = [&](size_t bytes) -> void* {
        void* p = ws + off;
        off += (bytes + 255) & ~(size_t)255;
        return p;
    };
    __bf16* Wg1   = (__bf16*)alloc(512 * 288 * 2);
    __bf16* W1p   = (__bf16*)alloc(1024 * 288 * 2);
    __bf16* W2b   = (__bf16*)alloc(1024 * 1024 * 2);
    __bf16* W3b   = (__bf16*)alloc(512 * 1024 * 2);
    __bf16* W4b   = (__bf16*)alloc(256 * 512 * 2);
    __bf16* Win_n = (__bf16*)alloc(256 * 32 * 2);
    __bf16* Whh_n = (__bf16*)alloc(256 * 256 * 2);
    float*  bsum  = (float*)alloc(512 * 4);
    float*  bihn  = (float*)alloc(256 * 4);
    float*  bhhn  = (float*)alloc(256 * 4);
    __bf16* x0    = (__bf16*)alloc((size_t)16384 * 288 * 2);
    __bf16* xA    = (__bf16*)alloc((size_t)16384 * 1024 * 2);
    __bf16* xB    = (__bf16*)alloc((size_t)16384 * 1024 * 2);

    prep_kernel<<<2048, 256, 0, stream>>>(W_ih, W_hh, b_ih, b_hh, W1, W2, W3, W4,
                                          Wg1, W1p, W2b, W3b, W4b, Win_n, Whh_n,
                                          bsum, bihn, bhhn);
    gru_kernel<<<256, 1024, 0, stream>>>(state, Wg1, Win_n, Whh_n, bhhn, x0);
    gemm_bias_act<<<dim3(128, 8), 256, 0, stream>>>(x0, W1p, b1, xA, 1024, 288, 1);
    gemm_bias_act<<<dim3(128, 8), 256, 0, stream>>>(xA, W2b, b2, xB, 1024, 1024, 1);
    gemm_bias_act<<<dim3(128, 4), 256, 0, stream>>>(xB, W3b, b3, xA, 512, 1024, 1);
    gemm_bias_act<<<dim3(128, 2), 256, 0, stream>>>(xA, W4b, b4, xB, 256, 512, 1);
    head_kernel<<<256, 256, 0, stream>>>(xB, Wp, bp, out);
}

// Round 14
// 433.451 us; speedup vs baseline: 1.2119x; 1.0009x over previous
//
#include <hip/hip_runtime.h>

// ---------------------------------------------------------------------------
// Actor: GRU over V=20 vehicle slots (H=256) + MLP head 271->1024->1024->512->256->1
// B=16384, F=15. All GEMMs in bf16 MFMA (16x16x32), fp32 accumulate.
//
// Round-28: GRU untouched (r11). GEMM K-loop: 2-buffer/2-barrier counted-
// vmcnt (r27, verified -7.2us) -> 3-buffer/1-barrier rotation. Iter k:
// vmcnt(4) [slab k landed, k+1 flying] -> s_barrier -> STAGE(k+2 -> buf
// (k+2)%3, the buffer read at iter k-1; safe because iter k-1's reads were
// consumed by MFMAs whose compiler lgkmcnt completed them before this
// barrier) -> FRAG_READ(k) [overlaps MFMAs via compiler auto-waits; no
// explicit lgkm] -> MFMA. Halves barrier count and removes the exposed
// ds_read latency. Cost: staging 48KB -> 3 blocks/CU (was 4).
// ---------------------------------------------------------------------------

typedef __attribute__((ext_vector_type(8))) __bf16 bf16x8;
typedef __attribute__((ext_vector_type(4))) __bf16 bf16x4;
typedef __attribute__((ext_vector_type(4))) float  floatx4;

#define MFMA16(a, b, c) __builtin_amdgcn_mfma_f32_16x16x32_bf16((a), (b), (c), 0, 0, 0)

#define GL_LDS16(g, l)                                                         \
    __builtin_amdgcn_global_load_lds(                                          \
        (const __attribute__((address_space(1))) void*)(g),                    \
        (__attribute__((address_space(3))) void*)(l), 16, 0, 0)

__device__ __forceinline__ float sigmoid_f(float x) { return 1.f / (1.f + __expf(-x)); }
__device__ __forceinline__ float tanh_f(float x)    { return 1.f - 2.f / (1.f + __expf(2.f * x)); }

// ---------------------------------------------------------------------------
// Weight prep:
//   Wg1  [512][288]  rows g in {r(0..255), z(256..511)}:
//        [W_ih[g][0..14] | bsum[g] | 0 x16 | W_hh[g][0..255]]   (col 15 = bias)
//   W1p  [1024][288] : [W1[o][0..14] | 0 x17 | W1[o][15..270]]
//   W2b  [1024][1024], W3b [512][1024], W4b [256][512]  : direct cvt
//   Win_n[256][32]   : [W_ih[512+j][0..14] | b_ih[512+j] | 0 x16] (col 15 = bias)
//   Whh_n[256][256]  : W_hh rows 512..767
//   bhhn [256] = b_hh[512+]
// ---------------------------------------------------------------------------
#define S0 147456u
#define S1 442368u
#define S2 1490944u
#define S3 2015232u
#define S4 2146304u
#define S5 2154496u
#define S6 2220032u
#define S7 2220544u
#define S8 2221056u

__global__ void prep_kernel(const float* __restrict__ W_ih, const float* __restrict__ W_hh,
                            const float* __restrict__ b_ih, const float* __restrict__ b_hh,
                            const float* __restrict__ W1, const float* __restrict__ W2,
                            const float* __restrict__ W3, const float* __restrict__ W4,
                            __bf16* __restrict__ Wg1, __bf16* __restrict__ W1p,
                            __bf16* __restrict__ W2b, __bf16* __restrict__ W3b,
                            __bf16* __restrict__ W4b, __bf16* __restrict__ Win_n,
                            __bf16* __restrict__ Whh_n, float* __restrict__ bsum,
                            float* __restrict__ bihn, float* __restrict__ bhhn)
{
    for (unsigned i = blockIdx.x * blockDim.x + threadIdx.x; i < S8; i += gridDim.x * blockDim.x) {
        if (i < S0) {
            unsigned g = i / 288u, c = i % 288u;
            float v;
            if (c < 15u)       v = W_ih[g * 15u + c];
            else if (c == 15u) v = b_ih[g] + b_hh[g];          // folded r/z bias
            else if (c < 32u)  v = 0.f;
            else               v = W_hh[g * 256u + (c - 32u)];
            Wg1[i] = (__bf16)v;
        } else if (i < S1) {
            unsigned t = i - S0, o = t / 288u, c = t % 288u;
            float v = (c < 15u) ? W1[o * 271u + c] : ((c < 32u) ? 0.f : W1[o * 271u + (c - 17u)]);
            W1p[t] = (__bf16)v;
        } else if (i < S2) {
            unsigned t = i - S1; W2b[t] = (__bf16)W2[t];
        } else if (i < S3) {
            unsigned t = i - S2; W3b[t] = (__bf16)W3[t];
        } else if (i < S4) {
            unsigned t = i - S3; W4b[t] = (__bf16)W4[t];
        } else if (i < S5) {
            unsigned t = i - S4, j = t / 32u, c = t % 32u;
            float v;
            if (c < 15u)       v = W_ih[(512u + j) * 15u + c];
            else if (c == 15u) v = b_ih[512u + j];             // folded xn bias
            else               v = 0.f;
            Win_n[t] = (__bf16)v;
        } else if (i < S6) {
            unsigned t = i - S5; Whh_n[t] = (__bf16)W_hh[512u * 256u + t];
        } else if (i < S7) {
            unsigned t = i - S6; bsum[t] = b_ih[t] + b_hh[t];
        } else {
            unsigned t = i - S7;
            if (t < 256u) bihn[t] = b_ih[512u + t];
            else          bhhn[t - 256u] = b_hh[512u + t - 256u];
        }
    }
}

// ---------------------------------------------------------------------------
// GRU kernel (r11, UNCHANGED). 256 blocks x 1024 threads (16 waves). 64 batch
// rows/block. Wave w owns gate cols w*16..w*16+15. Per step, 2 unroll-1
// passes:
//   p0: acc (ar,az) over all 4 nt (32 regs) -> sigmoid -> rzbuf[nt][tid]
//   p1: acc (axn,ahn) (32 regs) -> n=tanh(axn+r*(ahn+bhn)), h'=(1-z)n+z*h_old
// hbuf[2][64][264] double-buffered, 1 barrier/step. sbuf stride 40:
// 5*ln+q mod 8 covers all 8 bank groups -> conflict-free state reads.
// ---------------------------------------------------------------------------
#define HSTRIDE 264
#define HBUF_N  (64 * HSTRIDE)
#define SSTRIDE 40
#define SBUF_N  (64 * SSTRIDE)    // 2560 per buffer

__global__ __launch_bounds__(1024)
void gru_kernel(const float* __restrict__ state,
                const __bf16* __restrict__ Wg1,  const __bf16* __restrict__ Win_n,
                const __bf16* __restrict__ Whh_n,
                const float* __restrict__ bhhn, __bf16* __restrict__ x0)
{
    __shared__ __bf16 hbuf[2 * HBUF_N];        // 67584 B
    __shared__ __bf16 sbuf[2 * SBUF_N];        // 10240 B; k 16..39 zero, k15 = 1.0
    __shared__ __bf16 rzbuf[4 * 1024 * 8];     // 65536 B: [nt][tid][8] r0..3|z0..3

    const int tid  = threadIdx.x;
    const int wave = tid >> 6;    // 0..15 : j-tile
    const int lane = tid & 63;
    const int q    = lane >> 4;
    const int ln   = lane & 15;
    const int b0   = blockIdx.x * 64;

    {   // zero h buffer 0 and both sbuf buffers
        bf16x8 z = {};
        bf16x8* p = (bf16x8*)hbuf;
        #pragma unroll 3
        for (int i = tid; i < HBUF_N / 8; i += 1024) p[i] = z;
        if (tid < 2 * SBUF_N / 8) ((bf16x8*)sbuf)[tid] = z;
    }
    const int srow = tid >> 4, sk = tid & 15;   // 64 rows x 16 cols staging

    // bhn (other biases folded into weight col 15 against sbuf's 1.0 column)
    const floatx4 Bhn = *(const floatx4*)(bhhn + wave * 16 + q * 4);

    const int jr = wave * 16 + ln;
    const __bf16* wr = Wg1   + (size_t)jr * 288 + q * 8;
    const __bf16* wz = Wg1   + (size_t)(256 + jr) * 288 + q * 8;
    const __bf16* wx = Win_n + (size_t)jr * 32  + q * 8;
    const __bf16* wh = Whh_n + (size_t)jr * 256 + q * 8;

    const __bf16* hread  = hbuf + ln * HSTRIDE + q * 8;              // + nt*16*HSTRIDE
    __bf16*       hwrite = hbuf + ln * HSTRIDE + wave * 16 + q * 4;  // + nt*16*HSTRIDE
    const __bf16* sread  = sbuf + ln * SSTRIDE + q * 8;              // + nt*16*SSTRIDE
    __bf16*       rzw    = rzbuf + tid * 8;                          // + nt*8192

    // stage state slice v=0, then set the permanent 1.0 bias column (k=15)
    if (sk < 15)
        sbuf[srow * SSTRIDE + sk] = (__bf16)state[(size_t)(b0 + srow) * 300 + sk];
    if (tid < 128) sbuf[(tid >> 6) * SBUF_N + (tid & 63) * SSTRIDE + 15] = (__bf16)1.0f;
    __syncthreads();

#define GRU_STEP(v, SB)                                                          \
    {                                                                            \
        float snext = 0.f;                                                       \
        if ((v) < 19 && sk < 15)                                                 \
            snext = state[(size_t)(b0 + srow) * 300 + ((v) + 1) * 15 + sk];      \
        _Pragma("unroll 1")                                                      \
        for (int p = 0; p < 2; ++p) {                                            \
            floatx4 acc0[4], acc1[4];                                            \
            const floatx4 zf = {0.f, 0.f, 0.f, 0.f};                             \
            _Pragma("unroll")                                                    \
            for (int nt = 0; nt < 4; nt++) { acc0[nt] = zf; acc1[nt] = zf; }     \
            if (p == 0) {                                                        \
                {                                                                \
                    bf16x8 a0 = *(const bf16x8*)(wr);                            \
                    bf16x8 a1 = *(const bf16x8*)(wz);                            \
                    _Pragma("unroll")                                            \
                    for (int nt = 0; nt < 4; nt++) {                             \
                        bf16x8 b = *(const bf16x8*)(sread + (SB) * SBUF_N +      \
                                                    nt * (16 * SSTRIDE));        \
                        acc0[nt] = MFMA16(a0, b, acc0[nt]);                      \
                        acc1[nt] = MFMA16(a1, b, acc1[nt]);                      \
                    }                                                            \
                }                                                                \
                _Pragma("unroll")                                                \
                for (int kk = 0; kk < 8; ++kk) {                                 \
                    bf16x8 a0 = *(const bf16x8*)(wr + 32 + kk * 32);             \
                    bf16x8 a1 = *(const bf16x8*)(wz + 32 + kk * 32);             \
                    _Pragma("unroll")                                            \
                    for (int nt = 0; nt < 4; nt++) {                             \
                        bf16x8 b = *(const bf16x8*)(hread + (SB) * HBUF_N +      \
                                                    nt * (16 * HSTRIDE) +        \
                                                    kk * 32);                    \
                        acc0[nt] = MFMA16(a0, b, acc0[nt]);                      \
                        acc1[nt] = MFMA16(a1, b, acc1[nt]);                      \
                    }                                                            \
                }                                                                \
                _Pragma("unroll")                                                \
                for (int nt = 0; nt < 4; nt++) {                                 \
                    bf16x8 rz;                                                   \
                    _Pragma("unroll")                                            \
                    for (int r = 0; r < 4; r++) {                                \
                        rz[r]     = (__bf16)sigmoid_f(acc0[nt][r]);              \
                        rz[4 + r] = (__bf16)sigmoid_f(acc1[nt][r]);              \
                    }                                                            \
                    *(bf16x8*)(rzw + nt * 8192) = rz;                            \
                }                                                                \
            } else {                                                             \
                {                                                                \
                    bf16x8 a0 = *(const bf16x8*)(wx);                            \
                    _Pragma("unroll")                                            \
                    for (int nt = 0; nt < 4; nt++) {                             \
                        bf16x8 b = *(const bf16x8*)(sread + (SB) * SBUF_N +      \
                                                    nt * (16 * SSTRIDE));        \
                        acc0[nt] = MFMA16(a0, b, acc0[nt]);                      \
                    }                                                            \
                }                                                                \
                _Pragma("unroll")                                                \
                for (int kk = 0; kk < 8; ++kk) {                                 \
                    bf16x8 a1 = *(const bf16x8*)(wh + kk * 32);                  \
                    _Pragma("unroll")                                            \
                    for (int nt = 0; nt < 4; nt++) {                             \
                        bf16x8 b = *(const bf16x8*)(hread + (SB) * HBUF_N +      \
                                                    nt * (16 * HSTRIDE) +        \
                                                    kk * 32);                    \
                        acc1[nt] = MFMA16(a1, b, acc1[nt]);                      \
                    }                                                            \
                }                                                                \
                _Pragma("unroll")                                                \
                for (int nt = 0; nt < 4; nt++) {                                 \
                    bf16x8 rz = *(const bf16x8*)(rzw + nt * 8192);               \
                    bf16x4 ho = *(const bf16x4*)(hwrite + (SB) * HBUF_N +        \
                                                 nt * (16 * HSTRIDE));           \
                    bf16x4 hv;                                                   \
                    _Pragma("unroll")                                            \
                    for (int r = 0; r < 4; r++) {                                \
                        float rg = (float)rz[r];                                 \
                        float zg = (float)rz[4 + r];                             \
                        float nn = tanh_f(acc0[nt][r] +                          \
                                          rg * (acc1[nt][r] + Bhn[r]));          \
                        float hnew = (1.f - zg) * nn + zg * (float)ho[r];        \
                        hv[r] = (__bf16)hnew;                                    \
                    }                                                            \
                    *(bf16x4*)(hwrite + (1 - (SB)) * HBUF_N +                    \
                               nt * (16 * HSTRIDE)) = hv;                        \
                }                                                                \
            }                                                                    \
        }                                                                        \
        if ((v) < 19 && sk < 15)                                                 \
            sbuf[(1 - (SB)) * SBUF_N + srow * SSTRIDE + sk] = (__bf16)snext;     \
        __syncthreads();                                                         \
    }

    #pragma unroll 1
    for (int v2 = 0; v2 < 10; ++v2) {
        GRU_STEP(2 * v2,     0)
        GRU_STEP(2 * v2 + 1, 1)
    }
#undef GRU_STEP

    // ---- epilogue: final h is in hbuf buffer 0 (step 19 wrote 1-SB = 0) ----
    // x0 = [state[:,0,:] (15) | 0-pad to 32 | h (256)], coalesced b128 moves.
    {
        const int erow = tid >> 4, p = tid & 15;
        #pragma unroll
        for (int s = 0; s < 2; s++) {
            const int col = p * 8 + s * 128;
            *(bf16x8*)(x0 + (size_t)(b0 + erow) * 288 + 32 + col) =
                *(const bf16x8*)(hbuf + erow * HSTRIDE + col);
        }
    }
    #pragma unroll
    for (int t = 0; t < 2; t++) {
        int i = tid + t * 1024;
        int erow = i >> 5, c = i & 31;
        float s = (c < 15) ? state[(size_t)(b0 + erow) * 300 + c] : 0.f;
        x0[(size_t)(b0 + erow) * 288 + c] = (__bf16)s;
    }
}

// ---------------------------------------------------------------------------
// LDS-staged GEMM, BK=32, 3-buffer single-barrier counted-vmcnt pipeline:
// C = act(A[M][K] @ W[N][K]^T + bias), bf16. 256 thr (4 waves 2x2), tile
// 128x128. Iter k: vmcnt(4) [slab k landed, k+1 flying] -> s_barrier ->
// STAGE(k+2 -> buf (k+2)%3) [that buffer's readers finished before this
// barrier: their ds_reads completed via compiler lgkmcnt before the MFMAs
// that consumed them, all pre-barrier] -> FRAG_READ(k) [no explicit lgkm;
// overlaps MFMAs] -> MFMA. One barrier/slab (was 2). Staging 3x16KB=48KB
// -> 3 blocks/CU. Bounce (34.8KB) unions inside the 48KB staging region.
// ---------------------------------------------------------------------------
__global__ __launch_bounds__(256)
void gemm_bias_act(const __bf16* __restrict__ A, const __bf16* __restrict__ W,
                   const float* __restrict__ bias, __bf16* __restrict__ C,
                   int N, int K, int relu)
{
    __shared__ __bf16 smem[3 * 8192];            // 49152 B: buf b at b*8192 (A @0, B @4096)
    // epilogue bounce reuses first 17408 elems (128 x 136)

    const int tid  = threadIdx.x;
    const int wave = tid >> 6, lane = tid & 63;
    const int q = lane >> 4, ln = lane & 15;
    const int wm = wave >> 1, wn = wave & 1;
    const int arow0 = blockIdx.x * 128;
    const int bcol0 = blockIdx.y * 128;

    float bv[4];
    #pragma unroll
    for (int n = 0; n < 4; n++) bv[n] = bias[bcol0 + wn * 64 + n * 16 + ln];

    floatx4 acc[4][4];
    const floatx4 zf = {0.f, 0.f, 0.f, 0.f};
    #pragma unroll
    for (int m = 0; m < 4; m++)
        #pragma unroll
        for (int n = 0; n < 4; n++) acc[m][n] = zf;

    const int stg_row = wave * 16 + (lane >> 2);   // + rd*64
    const int stg_k   = (lane & 3) * 8;
    const int lds_off = wave * 512;                // + rd*2048

#define STAGE(kt, b)                                                            \
    {                                                                           \
        _Pragma("unroll")                                                       \
        for (int rd = 0; rd < 2; rd++) {                                        \
            GL_LDS16(A + (size_t)(arow0 + stg_row + rd * 64) * K + (kt) * 32 + stg_k, \
                     smem + (b) * 8192 + lds_off + rd * 2048);                  \
            GL_LDS16(W + (size_t)(bcol0 + stg_row + rd * 64) * K + (kt) * 32 + stg_k, \
                     smem + 4096 + (b) * 8192 + lds_off + rd * 2048);           \
        }                                                                       \
    }

#define FRAG_READ(b)                                                            \
    {                                                                           \
        _Pragma("unroll")                                                       \
        for (int m = 0; m < 4; m++)                                             \
            af[m] = *(const bf16x8*)(smem + (b) * 8192 +                        \
                                     (wm * 64 + m * 16 + ln) * 32 + q * 8);     \
        _Pragma("unroll")                                                       \
        for (int n = 0; n < 4; n++)                                             \
            bf[n] = *(const bf16x8*)(smem + 4096 + (b) * 8192 +                 \
                                     (wn * 64 + n * 16 + ln) * 32 + q * 8);     \
    }

#define FRAG_MFMA                                                               \
    {                                                                           \
        _Pragma("unroll")                                                       \
        for (int n = 0; n < 4; n++)                                             \
            _Pragma("unroll")                                                   \
            for (int m = 0; m < 4; m++)                                         \
                acc[m][n] = MFMA16(af[m], bf[n], acc[m][n]);                    \
    }

    const int nk = K >> 5;          // K multiple of 32 for all layers (nk >= 9)
    STAGE(0, 0)
    STAGE(1, 1)
    bf16x8 af[4], bf[4];
    int k = 0;
    int b3 = 2;                     // buffer index for slab k+2 (rotates 2,0,1,...)
    #pragma unroll 1
    for (; k + 2 < nk; ++k) {
        asm volatile("s_waitcnt vmcnt(4)" ::: "memory");   // slab k landed; k+1 flying
        __builtin_amdgcn_s_barrier();                      // all waves: slab-k writes visible,
        asm volatile("" ::: "memory");                     //   buf b3's readers all done (iter k-1)
        STAGE(k + 2, b3)                                   // overwrite the iter-(k-1) buffer
        {
            const int b = b3 == 2 ? 0 : (b3 == 0 ? 1 : 2); // (k)%3: b3 = (k+2)%3
            FRAG_READ(b)                                   // overlaps MFMAs (compiler auto-waits)
        }
        FRAG_MFMA
        b3 = (b3 == 2) ? 0 : b3 + 1;
    }
    {   // k == nk-2: slab nk-1 still flying, no further staging
        asm volatile("s_waitcnt vmcnt(4)" ::: "memory");
        __builtin_amdgcn_s_barrier();
        asm volatile("" ::: "memory");
        FRAG_READ((nk - 2) % 3)
        FRAG_MFMA
    }
    {   // k == nk-1: drain everything
        asm volatile("s_waitcnt vmcnt(0)" ::: "memory");
        __builtin_amdgcn_s_barrier();
        asm volatile("" ::: "memory");
        FRAG_READ((nk - 1) % 3)
        FRAG_MFMA
    }
    __syncthreads();                     // staging reads done -> bounce may reuse
#undef STAGE
#undef FRAG_READ
#undef FRAG_MFMA

    // epilogue: bias+act -> LDS bounce (stride 136) -> coalesced b128 stores
    #pragma unroll
    for (int m = 0; m < 4; m++)
        #pragma unroll
        for (int n = 0; n < 4; n++)
            #pragma unroll
            for (int r = 0; r < 4; r++) {
                float val = acc[m][n][r] + bv[n];
                if (relu) val = fmaxf(val, 0.f);
                smem[(wm * 64 + m * 16 + q * 4 + r) * 136 + wn * 64 + n * 16 + ln] = (__bf16)val;
            }
    __syncthreads();
    {
        const int row = tid >> 4, seg = tid & 15;
        #pragma unroll
        for (int p = 0; p < 8; p++) {
            const int rr = row + p * 16;
            *(bf16x8*)(C + (size_t)(arow0 + rr) * N + bcol0 + seg * 8) =
                *(const bf16x8*)(smem + rr * 136 + seg * 8);
        }
    }
}

// ---------------------------------------------------------------------------
// Head: out[b] = tanh(dot(x4[b][0..255], Wp) + bp).  4 lanes per row.
// ---------------------------------------------------------------------------
__global__ __launch_bounds__(256)
void head_kernel(const __bf16* __restrict__ x4, const float* __restrict__ Wp,
                 const float* __restrict__ bp, float* __restrict__ out)
{
    const int tid = threadIdx.x;
    const int wave = tid >> 6, lane = tid & 63;
    const int row = blockIdx.x * 64 + wave * 16 + (lane >> 2);
    const int part = lane & 3;
    const __bf16* xp = x4 + (size_t)row * 256 + part * 64;
    const float* wp = Wp + part * 64;
    float sum = 0.f;
    #pragma unroll
    for (int i = 0; i < 8; i++) {
        bf16x8 xv = *(const bf16x8*)(xp + i * 8);
        #pragma unroll
        for (int jj = 0; jj < 8; jj++) sum += (float)xv[jj] * wp[i * 8 + jj];
    }
    sum += __shfl_xor(sum, 1);
    sum += __shfl_xor(sum, 2);
    if (part == 0) out[row] = tanhf(sum + bp[0]);
}

// ---------------------------------------------------------------------------
extern "C" void kernel_launch(void* const* d_in, const int* in_sizes, int n_in,
                              void* d_out, int out_size, void* d_ws, size_t ws_size,
                              hipStream_t stream)
{
    const float* state = (const float*)d_in[0];
    const float* W_ih  = (const float*)d_in[1];
    const float* W_hh  = (const float*)d_in[2];
    const float* b_ih  = (const float*)d_in[3];
    const float* b_hh  = (const float*)d_in[4];
    const float* W1    = (const float*)d_in[5];
    const float* b1    = (const float*)d_in[6];
    const float* W2    = (const float*)d_in[7];
    const float* b2    = (const float*)d_in[8];
    const float* W3    = (const float*)d_in[9];
    const float* b3    = (const float*)d_in[10];
    const float* W4    = (const float*)d_in[11];
    const float* b4    = (const float*)d_in[12];
    const float* Wp    = (const float*)d_in[13];
    const float* bp    = (const float*)d_in[14];
    float* out = (float*)d_out;

    char* ws = (char*)d_ws;
    size_t off = 0;
    auto alloc = [&](size_t bytes) -> void* {
        void* p = ws + off;
        off += (bytes + 255) & ~(size_t)255;
        return p;
    };
    __bf16* Wg1   = (__bf16*)alloc(512 * 288 * 2);
    __bf16* W1p   = (__bf16*)alloc(1024 * 288 * 2);
    __bf16* W2b   = (__bf16*)alloc(1024 * 1024 * 2);
    __bf16* W3b   = (__bf16*)alloc(512 * 1024 * 2);
    __bf16* W4b   = (__bf16*)alloc(256 * 512 * 2);
    __bf16* Win_n = (__bf16*)alloc(256 * 32 * 2);
    __bf16* Whh_n = (__bf16*)alloc(256 * 256 * 2);
    float*  bsum  = (float*)alloc(512 * 4);
    float*  bihn  = (float*)alloc(256 * 4);
    float*  bhhn  = (float*)alloc(256 * 4);
    __bf16* x0    = (__bf16*)alloc((size_t)16384 * 288 * 2);
    __bf16* xA    = (__bf16*)alloc((size_t)16384 * 1024 * 2);
    __bf16* xB    = (__bf16*)alloc((size_t)16384 * 1024 * 2);

    prep_kernel<<<2048, 256, 0, stream>>>(W_ih, W_hh, b_ih, b_hh, W1, W2, W3, W4,
                                          Wg1, W1p, W2b, W3b, W4b, Win_n, Whh_n,
                                          bsum, bihn, bhhn);
    gru_kernel<<<256, 1024, 0, stream>>>(state, Wg1, Win_n, Whh_n, bhhn, x0);
    gemm_bias_act<<<dim3(128, 8), 256, 0, stream>>>(x0, W1p, b1, xA, 1024, 288, 1);
    gemm_bias_act<<<dim3(128, 8), 256, 0, stream>>>(xA, W2b, b2, xB, 1024, 1024, 1);
    gemm_bias_act<<<dim3(128, 4), 256, 0, stream>>>(xB, W3b, b3, xA, 512, 1024, 1);
    gemm_bias_act<<<dim3(128, 2), 256, 0, stream>>>(xA, W4b, b4, xB, 256, 512, 1);
    head_kernel<<<256, 256, 0, stream>>>(xB, Wp, bp, out);
}